// Round 9
// baseline (719.187 us; speedup 1.0000x reference)
//
#include <hip/hip_runtime.h>
#include <hip/hip_bf16.h>

typedef __bf16 bf16;
typedef __attribute__((ext_vector_type(8))) __bf16 bf16x8;
typedef __attribute__((ext_vector_type(4))) float f32x4;

constexpr int N_NODES   = 100000;
constexpr int N_PAD     = 100032;   // multiple of 64 (GEMM block tile)
constexpr int D         = 128;
constexpr int D_FF      = 256;
constexpr int N_CLASSES = 26;
constexpr int N_GRAPHS  = 512;
constexpr int NB1       = 256;                       // partition blocks
constexpr int NBUCK     = (N_NODES + 511) / 512;     // 196 dst-buckets of 512 nodes
constexpr int GB        = N_PAD / 64;                // 1563 gemm blocks
constexpr int GCN       = NBUCK * NB1;               // 50176

__device__ inline float2 bf2f(unsigned u) {
    float lo = __uint_as_float(u << 16);
    float hi = __uint_as_float(u & 0xffff0000u);
    return make_float2(lo, hi);
}

// ---------------- fused front-end: gemm1 || edge-histogram || starts ----------------
// blocks [0,GB): layer-1 GEMM (f32 input, in-register bf16 cast)
// blocks [GB,GB+NB1): per-block LDS histogram over dst buckets
// block GB+NB1: starts[g] = lower_bound(batch, g)
__global__ __launch_bounds__(256) void prep_kernel(const float* __restrict__ x,
                                                   const bf16* __restrict__ WT,
                                                   bf16* __restrict__ hA,
                                                   const int* __restrict__ edst,
                                                   int* __restrict__ gcount,
                                                   const int* __restrict__ batch,
                                                   int* __restrict__ starts,
                                                   int e, int n) {
    __shared__ int cnt[NBUCK];
    int bx = blockIdx.x;
    if (bx < GB) {
        // ---- layer-1 GEMM ----
        int wave = threadIdx.x >> 6;
        int lane = threadIdx.x & 63;
        int m16  = lane & 15;
        int quad = lane >> 4;
        int row0 = bx * 64 + wave * 16;
        int arowi = row0 + m16;

        bf16x8 a[4];
        const float* arow = x + (size_t)arowi * D + quad * 8;
#pragma unroll
        for (int kt = 0; kt < 4; ++kt) {
            float4 f0 = make_float4(0.f, 0.f, 0.f, 0.f);
            float4 f1 = make_float4(0.f, 0.f, 0.f, 0.f);
            if (arowi < n) {
                f0 = *(const float4*)(arow + kt * 32);
                f1 = *(const float4*)(arow + kt * 32 + 4);
            }
            bf16x8 v = { (bf16)f0.x, (bf16)f0.y, (bf16)f0.z, (bf16)f0.w,
                         (bf16)f1.x, (bf16)f1.y, (bf16)f1.z, (bf16)f1.w };
            a[kt] = v;
        }
#pragma unroll
        for (int nt = 0; nt < 8; ++nt) {
            f32x4 acc = {0.f, 0.f, 0.f, 0.f};
            const bf16* brow = WT + (nt * 16 + m16) * D + quad * 8;
#pragma unroll
            for (int kt = 0; kt < 4; ++kt) {
                bf16x8 b = *(const bf16x8*)(brow + kt * 32);
                acc = __builtin_amdgcn_mfma_f32_16x16x32_bf16(a[kt], b, acc, 0, 0, 0);
            }
#pragma unroll
            for (int r = 0; r < 4; ++r)
                hA[(row0 + quad * 4 + r) * D + nt * 16 + m16] = (bf16)acc[r];
        }
    } else if (bx < GB + NB1) {
        // ---- histogram over dst buckets ----
        int b = bx - GB;
        for (int t = threadIdx.x; t < NBUCK; t += 256) cnt[t] = 0;
        __syncthreads();
        int chunk = (e + NB1 - 1) / NB1;
        int lo = b * chunk;
        int hi = min(e, lo + chunk);
        for (int i = lo + threadIdx.x; i < hi; i += 256)
            atomicAdd(&cnt[edst[i] >> 9], 1);
        __syncthreads();
        for (int t = threadIdx.x; t < NBUCK; t += 256)
            gcount[t * NB1 + b] = cnt[t];
    } else {
        // ---- pooling segment starts (batch sorted) ----
        for (int g = threadIdx.x; g <= N_GRAPHS; g += 256) {
            int lo = 0, hi = n;
            while (lo < hi) {
                int mid = (lo + hi) >> 1;
                if (batch[mid] < g) lo = mid + 1; else hi = mid;
            }
            starts[g] = lo;
        }
    }
}

// single-block exclusive scan over GCN elements (replaces 3-kernel scan)
__global__ __launch_bounds__(1024) void scan_single(const int* __restrict__ in,
                                                    int* __restrict__ outx, int n) {
    __shared__ int sd[1024];
    int t = threadIdx.x;
    const int CH = (n + 1023) / 1024;
    int lo = t * CH, hi = min(n, lo + CH);
    int sum = 0;
    for (int i = lo; i < hi; ++i) sum += in[i];
    sd[t] = sum; __syncthreads();
    for (int off = 1; off < 1024; off <<= 1) {
        int v = (t >= off) ? sd[t - off] : 0;
        __syncthreads();
        sd[t] += v;
        __syncthreads();
    }
    int run = sd[t] - sum;   // exclusive prefix at chunk start
    for (int i = lo; i < hi; ++i) { int v = in[i]; outx[i] = run; run += v; }
}

// P3: scatter edges into bucket-contiguous ebuf; pack (src<<9)|(dst&511)
__global__ __launch_bounds__(512) void p3_scatter(const int* __restrict__ esrc,
                                                  const int* __restrict__ edst,
                                                  const int* __restrict__ gbase,
                                                  int* __restrict__ ebuf, int e) {
    __shared__ int cur[NBUCK];
    for (int t = threadIdx.x; t < NBUCK; t += 512)
        cur[t] = gbase[t * NB1 + blockIdx.x];
    __syncthreads();
    int chunk = (e + NB1 - 1) / NB1;
    int lo = blockIdx.x * chunk;
    int hi = min(e, lo + chunk);
    for (int i = lo + threadIdx.x; i < hi; i += 512) {
        int d = edst[i], s = esrc[i];
        int pos = atomicAdd(&cur[d >> 9], 1);   // LDS atomic
        ebuf[pos] = (s << 9) | (d & 511);
    }
}

// P45: fused per-bucket degree count + LDS scan + CSR fill (512 threads: 8 waves/CU)
__global__ __launch_bounds__(512) void p45_fill(const int* __restrict__ ebuf,
                                                const int* __restrict__ gbase,
                                                float* __restrict__ dinv,
                                                int* __restrict__ rowptr,
                                                int* __restrict__ csrc, int e, int n) {
    __shared__ int cnt[512];
    __shared__ int ps[512];
    __shared__ int cur[512];
    int b = blockIdx.x, t = threadIdx.x;
    cnt[t] = 0;
    __syncthreads();
    int lo = gbase[b * NB1];
    int hi = (b + 1 < NBUCK) ? gbase[(b + 1) * NB1] : e;
    for (int i = lo + t; i < hi; i += 512)
        atomicAdd(&cnt[ebuf[i] & 511], 1);      // LDS atomic
    __syncthreads();
    int a = cnt[t];
    ps[t] = a;
    __syncthreads();
    for (int off = 1; off < 512; off <<= 1) {
        int v = (t >= off) ? ps[t - off] : 0;
        __syncthreads();
        ps[t] += v;
        __syncthreads();
    }
    int g0 = lo + ps[t] - a;             // global CSR slot of node b*512+t
    int node = b * 512 + t;
    cur[t] = g0;
    if (node < n) {
        rowptr[node] = g0;
        dinv[node] = 1.0f / sqrtf((float)(a + 1));   // +1 self-loop
    }
    if (b == 0 && t == 0) rowptr[n] = e;
    __syncthreads();
    for (int i = lo + t; i < hi; i += 512) {
        int pe = ebuf[i];
        int pos = atomicAdd(&cur[pe & 511], 1);  // LDS atomic
        csrc[pos] = pe >> 9;
    }
}

// W[l][k][n] f32 -> WT3[l][n][k] bf16
__global__ void castWT3_kernel(const float* __restrict__ W0,
                               const float* __restrict__ W1,
                               const float* __restrict__ W2,
                               bf16* __restrict__ WT3) {
    int n = blockIdx.x, l = blockIdx.y, k = threadIdx.x;
    const float* W = (l == 0) ? W0 : (l == 1) ? W1 : W2;
    WT3[l * D * D + n * D + k] = (bf16)W[k * D + n];
}

// C[Mpad x 128] = A[Mpad x 128] @ W[128 x 128], bf16 in/out, no LDS.
__global__ __launch_bounds__(256) void gemm_kernel(const bf16* __restrict__ A,
                                                   const bf16* __restrict__ WT,
                                                   bf16* __restrict__ C) {
    int wave = threadIdx.x >> 6;
    int lane = threadIdx.x & 63;
    int m16  = lane & 15;
    int quad = lane >> 4;
    int row0 = blockIdx.x * 64 + wave * 16;

    bf16x8 a[4];
    const bf16* arow = A + (row0 + m16) * D + quad * 8;
#pragma unroll
    for (int kt = 0; kt < 4; ++kt)
        a[kt] = *(const bf16x8*)(arow + kt * 32);

#pragma unroll
    for (int nt = 0; nt < 8; ++nt) {
        f32x4 acc = {0.f, 0.f, 0.f, 0.f};
        const bf16* brow = WT + (nt * 16 + m16) * D + quad * 8;
#pragma unroll
        for (int kt = 0; kt < 4; ++kt) {
            bf16x8 b = *(const bf16x8*)(brow + kt * 32);
            acc = __builtin_amdgcn_mfma_f32_16x16x32_bf16(a[kt], b, acc, 0, 0, 0);
        }
#pragma unroll
        for (int r = 0; r < 4; ++r)
            C[(row0 + quad * 4 + r) * D + nt * 16 + m16] = (bf16)acc[r];
    }
}

// out[v][:] = relu( dinv[v]^2*h[v] + sum_e dinv[src]*dinv[v]*h[src] + bias )
// At the memory-side random-gather ceiling (R5-R8: 370MB @ 3.67TB/s) — frozen.
__global__ __launch_bounds__(256) void spmm_kernel(const bf16* __restrict__ h,
                                                   const int* __restrict__ rowptr,
                                                   const int* __restrict__ csrc,
                                                   const float* __restrict__ dinv,
                                                   const float* __restrict__ bias,
                                                   bf16* __restrict__ out, int n) {
    int v = blockIdx.x * 4 + (threadIdx.x >> 6);
    if (v >= n) return;
    int lane = threadIdx.x & 63;
    int g = lane >> 4;          // edge group 0..3
    int c = lane & 15;          // dim chunk: dims c*8 .. c*8+7
    int s = rowptr[v], e = rowptr[v + 1];
    float dv = dinv[v];

    float acc[8] = {0.f, 0.f, 0.f, 0.f, 0.f, 0.f, 0.f, 0.f};

    if (g == 0) {
        uint4 u = *(const uint4*)(h + v * D + c * 8);
        float s2 = dv * dv;
        float2 f0 = bf2f(u.x), f1 = bf2f(u.y), f2 = bf2f(u.z), f3 = bf2f(u.w);
        acc[0] = s2 * f0.x; acc[1] = s2 * f0.y;
        acc[2] = s2 * f1.x; acc[3] = s2 * f1.y;
        acc[4] = s2 * f2.x; acc[5] = s2 * f2.y;
        acc[6] = s2 * f3.x; acc[7] = s2 * f3.y;
    }

    int j = s + g;
    for (; j + 4 < e; j += 8) {
        int s0 = csrc[j], s1 = csrc[j + 4];
        float w0 = dinv[s0] * dv, w1 = dinv[s1] * dv;
        uint4 ua = *(const uint4*)(h + s0 * D + c * 8);
        uint4 ub = *(const uint4*)(h + s1 * D + c * 8);
        float2 a0 = bf2f(ua.x), a1 = bf2f(ua.y), a2 = bf2f(ua.z), a3 = bf2f(ua.w);
        float2 b0 = bf2f(ub.x), b1 = bf2f(ub.y), b2 = bf2f(ub.z), b3 = bf2f(ub.w);
        acc[0] = fmaf(w0, a0.x, acc[0]); acc[1] = fmaf(w0, a0.y, acc[1]);
        acc[2] = fmaf(w0, a1.x, acc[2]); acc[3] = fmaf(w0, a1.y, acc[3]);
        acc[4] = fmaf(w0, a2.x, acc[4]); acc[5] = fmaf(w0, a2.y, acc[5]);
        acc[6] = fmaf(w0, a3.x, acc[6]); acc[7] = fmaf(w0, a3.y, acc[7]);
        acc[0] = fmaf(w1, b0.x, acc[0]); acc[1] = fmaf(w1, b0.y, acc[1]);
        acc[2] = fmaf(w1, b1.x, acc[2]); acc[3] = fmaf(w1, b1.y, acc[3]);
        acc[4] = fmaf(w1, b2.x, acc[4]); acc[5] = fmaf(w1, b2.y, acc[5]);
        acc[6] = fmaf(w1, b3.x, acc[6]); acc[7] = fmaf(w1, b3.y, acc[7]);
    }
    if (j < e) {
        int s0 = csrc[j];
        float w0 = dinv[s0] * dv;
        uint4 ua = *(const uint4*)(h + s0 * D + c * 8);
        float2 a0 = bf2f(ua.x), a1 = bf2f(ua.y), a2 = bf2f(ua.z), a3 = bf2f(ua.w);
        acc[0] = fmaf(w0, a0.x, acc[0]); acc[1] = fmaf(w0, a0.y, acc[1]);
        acc[2] = fmaf(w0, a1.x, acc[2]); acc[3] = fmaf(w0, a1.y, acc[3]);
        acc[4] = fmaf(w0, a2.x, acc[4]); acc[5] = fmaf(w0, a2.y, acc[5]);
        acc[6] = fmaf(w0, a3.x, acc[6]); acc[7] = fmaf(w0, a3.y, acc[7]);
    }

#pragma unroll
    for (int d = 0; d < 8; ++d) {
        acc[d] += __shfl_xor(acc[d], 16);
        acc[d] += __shfl_xor(acc[d], 32);
    }

    if (g == 0) {
        float4 bi0 = *(const float4*)(bias + c * 8);
        float4 bi1 = *(const float4*)(bias + c * 8 + 4);
        bf16x8 o;
        o[0] = (bf16)fmaxf(acc[0] + bi0.x, 0.f);
        o[1] = (bf16)fmaxf(acc[1] + bi0.y, 0.f);
        o[2] = (bf16)fmaxf(acc[2] + bi0.z, 0.f);
        o[3] = (bf16)fmaxf(acc[3] + bi0.w, 0.f);
        o[4] = (bf16)fmaxf(acc[4] + bi1.x, 0.f);
        o[5] = (bf16)fmaxf(acc[5] + bi1.y, 0.f);
        o[6] = (bf16)fmaxf(acc[6] + bi1.z, 0.f);
        o[7] = (bf16)fmaxf(acc[7] + bi1.w, 0.f);
        *(bf16x8*)(out + v * D + c * 8) = o;
    }
}

// fused mean-pool + 2-layer FC head: one block per graph
__global__ __launch_bounds__(256) void poolfc_kernel(const bf16* __restrict__ h,
                                                     const int* __restrict__ starts,
                                                     const float* __restrict__ Wfc,
                                                     const float* __restrict__ bfc,
                                                     const float* __restrict__ Wfc2,
                                                     const float* __restrict__ bfc2,
                                                     float* __restrict__ out) {
    __shared__ float part[3][D];
    __shared__ float pr[D];
    __shared__ float hid[D_FF];
    int g = blockIdx.x;
    int w = threadIdx.x >> 6, lane = threadIdx.x & 63;
    int s = starts[g], e = starts[g + 1];
    float ax = 0.f, ay = 0.f;
    for (int r = s + w; r < e; r += 4) {
        unsigned u = *(const unsigned*)(h + r * D + lane * 2);
        float2 f = bf2f(u);
        ax += f.x; ay += f.y;
    }
    if (w > 0) { part[w - 1][lane * 2] = ax; part[w - 1][lane * 2 + 1] = ay; }
    __syncthreads();
    if (w == 0) {
#pragma unroll
        for (int k = 0; k < 3; ++k) { ax += part[k][lane * 2]; ay += part[k][lane * 2 + 1]; }
        float c = fmaxf((float)(e - s), 1.0f);
        pr[lane * 2]     = ax / c;
        pr[lane * 2 + 1] = ay / c;
    }
    __syncthreads();
    int t = threadIdx.x;
    float acc = bfc[t];
    for (int k = 0; k < D; ++k) acc = fmaf(pr[k], Wfc[k * D_FF + t], acc);
    hid[t] = fmaxf(acc, 0.f);
    __syncthreads();
    if (t < N_CLASSES) {
        float o = bfc2[t];
        for (int k = 0; k < D_FF; ++k) o = fmaf(hid[k], Wfc2[k * N_CLASSES + t], o);
        out[g * N_CLASSES + t] = o;
    }
}

// ---------------- launch ----------------

extern "C" void kernel_launch(void* const* d_in, const int* in_sizes, int n_in,
                              void* d_out, int out_size, void* d_ws, size_t ws_size,
                              hipStream_t stream) {
    const float* x     = (const float*)d_in[0];
    const int*   eidx  = (const int*)d_in[1];
    const int*   batch = (const int*)d_in[2];
    const float* W[3]  = { (const float*)d_in[3], (const float*)d_in[5], (const float*)d_in[7] };
    const float* b[3]  = { (const float*)d_in[4], (const float*)d_in[6], (const float*)d_in[8] };
    const float* Wfc   = (const float*)d_in[9];
    const float* bfc   = (const float*)d_in[10];
    const float* Wfc2  = (const float*)d_in[11];
    const float* bfc2  = (const float*)d_in[12];
    float* out = (float*)d_out;

    const int E = in_sizes[1] / 2;           // 3,200,000
    const int N = in_sizes[0] / D;           // 100,000
    const int* esrc = eidx;
    const int* edst = eidx + E;

    uint8_t* base = (uint8_t*)d_ws;
    size_t off = 0;
    auto alloc = [&](size_t bytes) -> void* {
        void* p = base + off;
        off = (off + bytes + 255) & ~(size_t)255;
        return p;
    };
    bf16*  hA     = (bf16*) alloc((size_t)N_PAD * D * 2);
    bf16*  hB     = (bf16*) alloc((size_t)N_PAD * D * 2);
    bf16*  WT3    = (bf16*) alloc((size_t)3 * D * D * 2);
    int*   csrc   = (int*)  alloc((size_t)E * 4);
    int*   ebuf   = (int*)  alloc((size_t)E * 4);
    int*   gcount = (int*)  alloc((size_t)GCN * 4);
    int*   gbase  = (int*)  alloc((size_t)(GCN + 1) * 4);
    int*   rowptr = (int*)  alloc((size_t)(N + 1) * 4);
    float* dinv   = (float*)alloc((size_t)N * 4);
    int*   starts = (int*)  alloc((size_t)(N_GRAPHS + 1) * 4);
    (void)ws_size; (void)n_in; (void)out_size;

    const int SB = (N + 3) / 4;              // spmm blocks

    // weights for all 3 layers (WT3 needed by prep's gemm part)
    castWT3_kernel<<<dim3(D, 3), D, 0, stream>>>(W[0], W[1], W[2], WT3);

    // fused: layer-1 gemm || edge histogram || starts
    prep_kernel<<<GB + NB1 + 1, 256, 0, stream>>>(x, WT3, hA, edst, gcount,
                                                  batch, starts, E, N);

    // CSR build
    scan_single<<<1, 1024, 0, stream>>>(gcount, gbase, GCN);
    p3_scatter<<<NB1, 512, 0, stream>>>(esrc, edst, gbase, ebuf, E);
    p45_fill<<<NBUCK, 512, 0, stream>>>(ebuf, gbase, dinv, rowptr, csrc, E, N);

    // layer 1 aggregation, then layers 2-3
    spmm_kernel<<<SB, 256, 0, stream>>>(hA, rowptr, csrc, dinv, b[0], hB, N);
    for (int l = 1; l < 3; ++l) {
        gemm_kernel<<<GB, 256, 0, stream>>>(hB, WT3 + (size_t)l * D * D, hA);
        spmm_kernel<<<SB, 256, 0, stream>>>(hA, rowptr, csrc, dinv, b[l], hB, N);
    }

    // fused mean-pool + FC head
    poolfc_kernel<<<N_GRAPHS, 256, 0, stream>>>(hB, starts, Wfc, bfc, Wfc2, bfc2, out);
}

// Round 10
// 676.933 us; speedup vs baseline: 1.0624x; 1.0624x over previous
//
#include <hip/hip_runtime.h>
#include <hip/hip_bf16.h>

typedef __bf16 bf16;
typedef __attribute__((ext_vector_type(8))) __bf16 bf16x8;
typedef __attribute__((ext_vector_type(4))) float f32x4;

constexpr int N_NODES   = 100000;
constexpr int N_PAD     = 100032;   // multiple of 64 (GEMM block tile)
constexpr int D         = 128;
constexpr int D_FF      = 256;
constexpr int N_CLASSES = 26;
constexpr int N_GRAPHS  = 512;
constexpr int NB1       = 1024;                      // partition blocks
constexpr int NBUCK     = (N_NODES + 511) / 512;     // 196 dst-buckets of 512 nodes

__device__ inline float2 bf2f(unsigned u) {
    float lo = __uint_as_float(u << 16);
    float hi = __uint_as_float(u & 0xffff0000u);
    return make_float2(lo, hi);
}

// ---------------- CSR build: atomic-free bucket counting sort ----------------

// P1: per-block LDS histogram over dst buckets (bucket = dst >> 9)
__global__ __launch_bounds__(256) void p1_hist(const int* __restrict__ edst,
                                               int* __restrict__ gcount, int e) {
    __shared__ int cnt[NBUCK];
    for (int t = threadIdx.x; t < NBUCK; t += 256) cnt[t] = 0;
    __syncthreads();
    int chunk = (e + NB1 - 1) / NB1;
    int lo = blockIdx.x * chunk;
    int hi = min(e, lo + chunk);
    for (int i = lo + threadIdx.x; i < hi; i += 256)
        atomicAdd(&cnt[edst[i] >> 9], 1);
    __syncthreads();
    for (int t = threadIdx.x; t < NBUCK; t += 256)
        gcount[t * NB1 + blockIdx.x] = cnt[t];
}

// 3-phase exclusive scan: out[0]=0, out[i+1]=incl[i] (+ block offsets)
__global__ __launch_bounds__(256) void scan1(const int* __restrict__ in,
                                             int* out, int* bsum, int n) {
    __shared__ int sd[256];
    int i = blockIdx.x * 256 + threadIdx.x;
    int v = (i < n) ? in[i] : 0;
    sd[threadIdx.x] = v; __syncthreads();
    for (int off = 1; off < 256; off <<= 1) {
        int t = (threadIdx.x >= off) ? sd[threadIdx.x - off] : 0;
        __syncthreads();
        sd[threadIdx.x] += t;
        __syncthreads();
    }
    if (i < n) out[i + 1] = sd[threadIdx.x];
    if (threadIdx.x == 255) bsum[blockIdx.x] = sd[255];
}

__global__ __launch_bounds__(1024) void scan2(const int* __restrict__ bsum,
                                              int* boff, int nb) {
    __shared__ int sd[1024];
    int t = threadIdx.x;
    int v = (t < nb) ? bsum[t] : 0;
    sd[t] = v; __syncthreads();
    for (int off = 1; off < 1024; off <<= 1) {
        int x = (t >= off) ? sd[t - off] : 0;
        __syncthreads();
        sd[t] += x;
        __syncthreads();
    }
    if (t < nb) boff[t] = sd[t] - v;  // exclusive
}

__global__ void scan3(int* out, const int* __restrict__ boff, int n) {
    int i = blockIdx.x * 256 + threadIdx.x;
    if (i < n) out[i + 1] += boff[blockIdx.x];
    if (i == 0) out[0] = 0;
}

// P3: scatter edges into bucket-contiguous ebuf; pack (src<<9)|(dst&511)
__global__ __launch_bounds__(256) void p3_scatter(const int* __restrict__ esrc,
                                                  const int* __restrict__ edst,
                                                  const int* __restrict__ gbase,
                                                  int* __restrict__ ebuf, int e) {
    __shared__ int cur[NBUCK];
    for (int t = threadIdx.x; t < NBUCK; t += 256)
        cur[t] = gbase[t * NB1 + blockIdx.x];
    __syncthreads();
    int chunk = (e + NB1 - 1) / NB1;
    int lo = blockIdx.x * chunk;
    int hi = min(e, lo + chunk);
    for (int i = lo + threadIdx.x; i < hi; i += 256) {
        int d = edst[i], s = esrc[i];
        int pos = atomicAdd(&cur[d >> 9], 1);   // LDS atomic
        ebuf[pos] = (s << 9) | (d & 511);
    }
}

// P45: fused per-bucket degree count + LDS scan + CSR fill
__global__ __launch_bounds__(256) void p45_fill(const int* __restrict__ ebuf,
                                                const int* __restrict__ gbase,
                                                float* __restrict__ dinv,
                                                int* __restrict__ rowptr,
                                                int* __restrict__ csrc, int e, int n) {
    __shared__ int cnt[512];
    __shared__ int ps[256];
    __shared__ int cur[512];
    int b = blockIdx.x, t = threadIdx.x;
    cnt[t] = 0; cnt[t + 256] = 0;
    __syncthreads();
    int lo = gbase[b * NB1];
    int hi = (b + 1 < NBUCK) ? gbase[(b + 1) * NB1] : e;
    for (int i = lo + t; i < hi; i += 256)
        atomicAdd(&cnt[ebuf[i] & 511], 1);      // LDS atomic
    __syncthreads();
    int a0 = cnt[t * 2], a1 = cnt[t * 2 + 1];
    ps[t] = a0 + a1;
    __syncthreads();
    for (int off = 1; off < 256; off <<= 1) {
        int v = (t >= off) ? ps[t - off] : 0;
        __syncthreads();
        ps[t] += v;
        __syncthreads();
    }
    int pexcl = (t > 0) ? ps[t - 1] : 0;
    int g0 = lo + pexcl;                 // global CSR slot of node b*512+2t
    int node0 = b * 512 + t * 2;
    cur[t * 2] = g0;
    cur[t * 2 + 1] = g0 + a0;
    if (node0 < n) {
        rowptr[node0] = g0;
        dinv[node0] = 1.0f / sqrtf((float)(a0 + 1));   // +1 self-loop
    }
    if (node0 + 1 < n) {
        rowptr[node0 + 1] = g0 + a0;
        dinv[node0 + 1] = 1.0f / sqrtf((float)(a1 + 1));
    }
    if (b == 0 && t == 0) rowptr[n] = e;
    __syncthreads();
    for (int i = lo + t; i < hi; i += 256) {
        int pe = ebuf[i];
        int pos = atomicAdd(&cur[pe & 511], 1);  // LDS atomic
        csrc[pos] = pe >> 9;
    }
}

// ---------------- pooling index: starts[g] = lower_bound(batch, g) ----------------
__global__ __launch_bounds__(576) void starts_kernel(const int* __restrict__ batch,
                                                     int* __restrict__ starts, int n) {
    int g = threadIdx.x;
    if (g > N_GRAPHS) return;
    int lo = 0, hi = n;
    while (lo < hi) {
        int mid = (lo + hi) >> 1;
        if (batch[mid] < g) lo = mid + 1; else hi = mid;
    }
    starts[g] = lo;
}

// ---------------- dense compute ----------------

// W[l][k][n] f32 -> WT3[l][n][k] bf16
__global__ void castWT3_kernel(const float* __restrict__ W0,
                               const float* __restrict__ W1,
                               const float* __restrict__ W2,
                               bf16* __restrict__ WT3) {
    int n = blockIdx.x, l = blockIdx.y, k = threadIdx.x;
    const float* W = (l == 0) ? W0 : (l == 1) ? W1 : W2;
    WT3[l * D * D + n * D + k] = (bf16)W[k * D + n];
}

// C[Mpad x 128] = A[Mpad x 128] @ W[128 x 128], bf16 in/out, no LDS.
__global__ __launch_bounds__(256) void gemm_kernel(const bf16* __restrict__ A,
                                                   const bf16* __restrict__ WT,
                                                   bf16* __restrict__ C) {
    int wave = threadIdx.x >> 6;
    int lane = threadIdx.x & 63;
    int m16  = lane & 15;
    int quad = lane >> 4;
    int row0 = blockIdx.x * 64 + wave * 16;

    bf16x8 a[4];
    const bf16* arow = A + (row0 + m16) * D + quad * 8;
#pragma unroll
    for (int kt = 0; kt < 4; ++kt)
        a[kt] = *(const bf16x8*)(arow + kt * 32);

#pragma unroll
    for (int nt = 0; nt < 8; ++nt) {
        f32x4 acc = {0.f, 0.f, 0.f, 0.f};
        const bf16* brow = WT + (nt * 16 + m16) * D + quad * 8;
#pragma unroll
        for (int kt = 0; kt < 4; ++kt) {
            bf16x8 b = *(const bf16x8*)(brow + kt * 32);
            acc = __builtin_amdgcn_mfma_f32_16x16x32_bf16(a[kt], b, acc, 0, 0, 0);
        }
#pragma unroll
        for (int r = 0; r < 4; ++r)
            C[(row0 + quad * 4 + r) * D + nt * 16 + m16] = (bf16)acc[r];
    }
}

// Layer-1 variant: A is f32 (the raw input x); cast to bf16 in-register.
__global__ __launch_bounds__(256) void gemm_f32_kernel(const float* __restrict__ A,
                                                       const bf16* __restrict__ WT,
                                                       bf16* __restrict__ C, int n) {
    int wave = threadIdx.x >> 6;
    int lane = threadIdx.x & 63;
    int m16  = lane & 15;
    int quad = lane >> 4;
    int row0 = blockIdx.x * 64 + wave * 16;
    int arowi = row0 + m16;

    bf16x8 a[4];
    const float* arow = A + (size_t)arowi * D + quad * 8;
#pragma unroll
    for (int kt = 0; kt < 4; ++kt) {
        float4 f0 = make_float4(0.f, 0.f, 0.f, 0.f);
        float4 f1 = make_float4(0.f, 0.f, 0.f, 0.f);
        if (arowi < n) {
            f0 = *(const float4*)(arow + kt * 32);
            f1 = *(const float4*)(arow + kt * 32 + 4);
        }
        bf16x8 v = { (bf16)f0.x, (bf16)f0.y, (bf16)f0.z, (bf16)f0.w,
                     (bf16)f1.x, (bf16)f1.y, (bf16)f1.z, (bf16)f1.w };
        a[kt] = v;
    }

#pragma unroll
    for (int nt = 0; nt < 8; ++nt) {
        f32x4 acc = {0.f, 0.f, 0.f, 0.f};
        const bf16* brow = WT + (nt * 16 + m16) * D + quad * 8;
#pragma unroll
        for (int kt = 0; kt < 4; ++kt) {
            bf16x8 b = *(const bf16x8*)(brow + kt * 32);
            acc = __builtin_amdgcn_mfma_f32_16x16x32_bf16(a[kt], b, acc, 0, 0, 0);
        }
#pragma unroll
        for (int r = 0; r < 4; ++r)
            C[(row0 + quad * 4 + r) * D + nt * 16 + m16] = (bf16)acc[r];
    }
}

// out[v][:] = relu( dinv[v]^2*h[v] + sum_e dinv[src]*dinv[v]*h[src] + bias )
// At the memory-side random-gather ceiling (R5-R9: 370MB @ 3.67TB/s) — frozen.
__global__ __launch_bounds__(256) void spmm_kernel(const bf16* __restrict__ h,
                                                   const int* __restrict__ rowptr,
                                                   const int* __restrict__ csrc,
                                                   const float* __restrict__ dinv,
                                                   const float* __restrict__ bias,
                                                   bf16* __restrict__ out, int n) {
    int v = blockIdx.x * 4 + (threadIdx.x >> 6);
    if (v >= n) return;
    int lane = threadIdx.x & 63;
    int g = lane >> 4;          // edge group 0..3
    int c = lane & 15;          // dim chunk: dims c*8 .. c*8+7
    int s = rowptr[v], e = rowptr[v + 1];
    float dv = dinv[v];

    float acc[8] = {0.f, 0.f, 0.f, 0.f, 0.f, 0.f, 0.f, 0.f};

    if (g == 0) {
        uint4 u = *(const uint4*)(h + v * D + c * 8);
        float s2 = dv * dv;
        float2 f0 = bf2f(u.x), f1 = bf2f(u.y), f2 = bf2f(u.z), f3 = bf2f(u.w);
        acc[0] = s2 * f0.x; acc[1] = s2 * f0.y;
        acc[2] = s2 * f1.x; acc[3] = s2 * f1.y;
        acc[4] = s2 * f2.x; acc[5] = s2 * f2.y;
        acc[6] = s2 * f3.x; acc[7] = s2 * f3.y;
    }

    int j = s + g;
    for (; j + 4 < e; j += 8) {
        int s0 = csrc[j], s1 = csrc[j + 4];
        float w0 = dinv[s0] * dv, w1 = dinv[s1] * dv;
        uint4 ua = *(const uint4*)(h + s0 * D + c * 8);
        uint4 ub = *(const uint4*)(h + s1 * D + c * 8);
        float2 a0 = bf2f(ua.x), a1 = bf2f(ua.y), a2 = bf2f(ua.z), a3 = bf2f(ua.w);
        float2 b0 = bf2f(ub.x), b1 = bf2f(ub.y), b2 = bf2f(ub.z), b3 = bf2f(ub.w);
        acc[0] = fmaf(w0, a0.x, acc[0]); acc[1] = fmaf(w0, a0.y, acc[1]);
        acc[2] = fmaf(w0, a1.x, acc[2]); acc[3] = fmaf(w0, a1.y, acc[3]);
        acc[4] = fmaf(w0, a2.x, acc[4]); acc[5] = fmaf(w0, a2.y, acc[5]);
        acc[6] = fmaf(w0, a3.x, acc[6]); acc[7] = fmaf(w0, a3.y, acc[7]);
        acc[0] = fmaf(w1, b0.x, acc[0]); acc[1] = fmaf(w1, b0.y, acc[1]);
        acc[2] = fmaf(w1, b1.x, acc[2]); acc[3] = fmaf(w1, b1.y, acc[3]);
        acc[4] = fmaf(w1, b2.x, acc[4]); acc[5] = fmaf(w1, b2.y, acc[5]);
        acc[6] = fmaf(w1, b3.x, acc[6]); acc[7] = fmaf(w1, b3.y, acc[7]);
    }
    if (j < e) {
        int s0 = csrc[j];
        float w0 = dinv[s0] * dv;
        uint4 ua = *(const uint4*)(h + s0 * D + c * 8);
        float2 a0 = bf2f(ua.x), a1 = bf2f(ua.y), a2 = bf2f(ua.z), a3 = bf2f(ua.w);
        acc[0] = fmaf(w0, a0.x, acc[0]); acc[1] = fmaf(w0, a0.y, acc[1]);
        acc[2] = fmaf(w0, a1.x, acc[2]); acc[3] = fmaf(w0, a1.y, acc[3]);
        acc[4] = fmaf(w0, a2.x, acc[4]); acc[5] = fmaf(w0, a2.y, acc[5]);
        acc[6] = fmaf(w0, a3.x, acc[6]); acc[7] = fmaf(w0, a3.y, acc[7]);
    }

#pragma unroll
    for (int d = 0; d < 8; ++d) {
        acc[d] += __shfl_xor(acc[d], 16);
        acc[d] += __shfl_xor(acc[d], 32);
    }

    if (g == 0) {
        float4 bi0 = *(const float4*)(bias + c * 8);
        float4 bi1 = *(const float4*)(bias + c * 8 + 4);
        bf16x8 o;
        o[0] = (bf16)fmaxf(acc[0] + bi0.x, 0.f);
        o[1] = (bf16)fmaxf(acc[1] + bi0.y, 0.f);
        o[2] = (bf16)fmaxf(acc[2] + bi0.z, 0.f);
        o[3] = (bf16)fmaxf(acc[3] + bi0.w, 0.f);
        o[4] = (bf16)fmaxf(acc[4] + bi1.x, 0.f);
        o[5] = (bf16)fmaxf(acc[5] + bi1.y, 0.f);
        o[6] = (bf16)fmaxf(acc[6] + bi1.z, 0.f);
        o[7] = (bf16)fmaxf(acc[7] + bi1.w, 0.f);
        *(bf16x8*)(out + v * D + c * 8) = o;
    }
}

// fused mean-pool + 2-layer FC head: one block per graph
__global__ __launch_bounds__(256) void poolfc_kernel(const bf16* __restrict__ h,
                                                     const int* __restrict__ starts,
                                                     const float* __restrict__ Wfc,
                                                     const float* __restrict__ bfc,
                                                     const float* __restrict__ Wfc2,
                                                     const float* __restrict__ bfc2,
                                                     float* __restrict__ out) {
    __shared__ float part[3][D];
    __shared__ float pr[D];
    __shared__ float hid[D_FF];
    int g = blockIdx.x;
    int w = threadIdx.x >> 6, lane = threadIdx.x & 63;
    int s = starts[g], e = starts[g + 1];
    float ax = 0.f, ay = 0.f;
    for (int r = s + w; r < e; r += 4) {
        unsigned u = *(const unsigned*)(h + r * D + lane * 2);
        float2 f = bf2f(u);
        ax += f.x; ay += f.y;
    }
    if (w > 0) { part[w - 1][lane * 2] = ax; part[w - 1][lane * 2 + 1] = ay; }
    __syncthreads();
    if (w == 0) {
#pragma unroll
        for (int k = 0; k < 3; ++k) { ax += part[k][lane * 2]; ay += part[k][lane * 2 + 1]; }
        float c = fmaxf((float)(e - s), 1.0f);
        pr[lane * 2]     = ax / c;
        pr[lane * 2 + 1] = ay / c;
    }
    __syncthreads();
    int t = threadIdx.x;
    float acc = bfc[t];
    for (int k = 0; k < D; ++k) acc = fmaf(pr[k], Wfc[k * D_FF + t], acc);
    hid[t] = fmaxf(acc, 0.f);
    __syncthreads();
    if (t < N_CLASSES) {
        float o = bfc2[t];
        for (int k = 0; k < D_FF; ++k) o = fmaf(hid[k], Wfc2[k * N_CLASSES + t], o);
        out[g * N_CLASSES + t] = o;
    }
}

// ---------------- launch ----------------

extern "C" void kernel_launch(void* const* d_in, const int* in_sizes, int n_in,
                              void* d_out, int out_size, void* d_ws, size_t ws_size,
                              hipStream_t stream) {
    const float* x     = (const float*)d_in[0];
    const int*   eidx  = (const int*)d_in[1];
    const int*   batch = (const int*)d_in[2];
    const float* W[3]  = { (const float*)d_in[3], (const float*)d_in[5], (const float*)d_in[7] };
    const float* b[3]  = { (const float*)d_in[4], (const float*)d_in[6], (const float*)d_in[8] };
    const float* Wfc   = (const float*)d_in[9];
    const float* bfc   = (const float*)d_in[10];
    const float* Wfc2  = (const float*)d_in[11];
    const float* bfc2  = (const float*)d_in[12];
    float* out = (float*)d_out;

    const int E = in_sizes[1] / 2;           // 3,200,000
    const int N = in_sizes[0] / D;           // 100,000
    const int* esrc = eidx;
    const int* edst = eidx + E;

    uint8_t* base = (uint8_t*)d_ws;
    size_t off = 0;
    auto alloc = [&](size_t bytes) -> void* {
        void* p = base + off;
        off = (off + bytes + 255) & ~(size_t)255;
        return p;
    };
    bf16*  hA     = (bf16*) alloc((size_t)N_PAD * D * 2);
    bf16*  hB     = (bf16*) alloc((size_t)N_PAD * D * 2);
    bf16*  WT3    = (bf16*) alloc((size_t)3 * D * D * 2);
    int*   csrc   = (int*)  alloc((size_t)E * 4);
    int*   ebuf   = (int*)  alloc((size_t)E * 4);
    int*   gcount = (int*)  alloc((size_t)NBUCK * NB1 * 4);
    int*   gbase  = (int*)  alloc((size_t)(NBUCK * NB1 + 1) * 4);
    int*   rowptr = (int*)  alloc((size_t)(N + 1) * 4);
    float* dinv   = (float*)alloc((size_t)N * 4);
    int*   bsum   = (int*)  alloc(4096);
    int*   boff   = (int*)  alloc(4096);
    int*   starts = (int*)  alloc((size_t)(N_GRAPHS + 1) * 4);
    (void)ws_size; (void)n_in; (void)out_size;

    const int GB  = N_PAD / 64;                         // 1563
    const int SB  = (N + 3) / 4;                        // spmm blocks
    const int GCN = NBUCK * NB1;                        // 200704
    const int GCB = (GCN + 255) / 256;                  // 784

    // CSR build (atomic-free, LDS counting sort) — R8 configuration
    p1_hist<<<NB1, 256, 0, stream>>>(edst, gcount, E);
    scan1<<<GCB, 256, 0, stream>>>(gcount, gbase, bsum, GCN);
    scan2<<<1, 1024, 0, stream>>>(bsum, boff, GCB);
    scan3<<<GCB, 256, 0, stream>>>(gbase, boff, GCN);
    p3_scatter<<<NB1, 256, 0, stream>>>(esrc, edst, gbase, ebuf, E);
    p45_fill<<<NBUCK, 256, 0, stream>>>(ebuf, gbase, dinv, rowptr, csrc, E, N);

    // pooling segments: parallel binary search
    starts_kernel<<<1, 576, 0, stream>>>(batch, starts, N);

    // weights for all 3 layers
    castWT3_kernel<<<dim3(D, 3), D, 0, stream>>>(W[0], W[1], W[2], WT3);

    // layer 1 (f32 input, in-register cast), then layers 2-3
    gemm_f32_kernel<<<GB, 256, 0, stream>>>(x, WT3, hA, N);
    spmm_kernel<<<SB, 256, 0, stream>>>(hA, rowptr, csrc, dinv, b[0], hB, N);
    for (int l = 1; l < 3; ++l) {
        gemm_kernel<<<GB, 256, 0, stream>>>(hB, WT3 + (size_t)l * D * D, hA);
        spmm_kernel<<<SB, 256, 0, stream>>>(hA, rowptr, csrc, dinv, b[l], hB, N);
    }

    // fused mean-pool + FC head
    poolfc_kernel<<<N_GRAPHS, 256, 0, stream>>>(hB, starts, Wfc, bfc, Wfc2, bfc2, out);
}

// Round 11
// 666.847 us; speedup vs baseline: 1.0785x; 1.0151x over previous
//
#include <hip/hip_runtime.h>
#include <hip/hip_bf16.h>

typedef __bf16 bf16;
typedef __attribute__((ext_vector_type(8))) __bf16 bf16x8;
typedef __attribute__((ext_vector_type(4))) float f32x4;

constexpr int N_NODES   = 100000;
constexpr int N_PAD     = 100032;   // multiple of 64 (GEMM block tile)
constexpr int D         = 128;
constexpr int D_FF      = 256;
constexpr int N_CLASSES = 26;
constexpr int N_GRAPHS  = 512;
constexpr int NB1       = 1024;                      // partition blocks
constexpr int NBUCK     = (N_NODES + 511) / 512;     // 196 dst-buckets of 512 nodes

__device__ inline float2 bf2f(unsigned u) {
    float lo = __uint_as_float(u << 16);
    float hi = __uint_as_float(u & 0xffff0000u);
    return make_float2(lo, hi);
}

// ---------------- CSR build: atomic-free bucket counting sort ----------------

// P1: per-block LDS histogram over dst buckets (bucket = dst >> 9)
__global__ __launch_bounds__(256) void p1_hist(const int* __restrict__ edst,
                                               int* __restrict__ gcount, int e) {
    __shared__ int cnt[NBUCK];
    for (int t = threadIdx.x; t < NBUCK; t += 256) cnt[t] = 0;
    __syncthreads();
    int chunk = (e + NB1 - 1) / NB1;
    int lo = blockIdx.x * chunk;
    int hi = min(e, lo + chunk);
    for (int i = lo + threadIdx.x; i < hi; i += 256)
        atomicAdd(&cnt[edst[i] >> 9], 1);
    __syncthreads();
    for (int t = threadIdx.x; t < NBUCK; t += 256)
        gcount[t * NB1 + blockIdx.x] = cnt[t];
}

// 3-phase exclusive scan: out[0]=0, out[i+1]=incl[i] (+ block offsets)
__global__ __launch_bounds__(256) void scan1(const int* __restrict__ in,
                                             int* out, int* bsum, int n) {
    __shared__ int sd[256];
    int i = blockIdx.x * 256 + threadIdx.x;
    int v = (i < n) ? in[i] : 0;
    sd[threadIdx.x] = v; __syncthreads();
    for (int off = 1; off < 256; off <<= 1) {
        int t = (threadIdx.x >= off) ? sd[threadIdx.x - off] : 0;
        __syncthreads();
        sd[threadIdx.x] += t;
        __syncthreads();
    }
    if (i < n) out[i + 1] = sd[threadIdx.x];
    if (threadIdx.x == 255) bsum[blockIdx.x] = sd[255];
}

__global__ __launch_bounds__(1024) void scan2(const int* __restrict__ bsum,
                                              int* boff, int nb) {
    __shared__ int sd[1024];
    int t = threadIdx.x;
    int v = (t < nb) ? bsum[t] : 0;
    sd[t] = v; __syncthreads();
    for (int off = 1; off < 1024; off <<= 1) {
        int x = (t >= off) ? sd[t - off] : 0;
        __syncthreads();
        sd[t] += x;
        __syncthreads();
    }
    if (t < nb) boff[t] = sd[t] - v;  // exclusive
}

__global__ void scan3(int* out, const int* __restrict__ boff, int n) {
    int i = blockIdx.x * 256 + threadIdx.x;
    if (i < n) out[i + 1] += boff[blockIdx.x];
    if (i == 0) out[0] = 0;
}

// P3: scatter edges into bucket-contiguous ebuf; pack (src<<9)|(dst&511)
__global__ __launch_bounds__(256) void p3_scatter(const int* __restrict__ esrc,
                                                  const int* __restrict__ edst,
                                                  const int* __restrict__ gbase,
                                                  int* __restrict__ ebuf, int e) {
    __shared__ int cur[NBUCK];
    for (int t = threadIdx.x; t < NBUCK; t += 256)
        cur[t] = gbase[t * NB1 + blockIdx.x];
    __syncthreads();
    int chunk = (e + NB1 - 1) / NB1;
    int lo = blockIdx.x * chunk;
    int hi = min(e, lo + chunk);
    for (int i = lo + threadIdx.x; i < hi; i += 256) {
        int d = edst[i], s = esrc[i];
        int pos = atomicAdd(&cur[d >> 9], 1);   // LDS atomic
        ebuf[pos] = (s << 9) | (d & 511);
    }
}

// P45: fused per-bucket degree count + LDS scan + CSR fill.
// 1024 threads (R11 change): 196 blocks is only 0.77 blocks/CU, so per-block
// TLP is the only latency-hiding available — 16 waves/block, 4x fewer
// edge-loop iterations. Barriers stay block-uniform (work masked by t<512).
__global__ __launch_bounds__(1024) void p45_fill(const int* __restrict__ ebuf,
                                                 const int* __restrict__ gbase,
                                                 float* __restrict__ dinv,
                                                 int* __restrict__ rowptr,
                                                 int* __restrict__ csrc, int e, int n) {
    __shared__ int cnt[512];
    __shared__ int ps[512];
    __shared__ int cur[512];
    int b = blockIdx.x, t = threadIdx.x;
    if (t < 512) cnt[t] = 0;
    __syncthreads();
    int lo = gbase[b * NB1];
    int hi = (b + 1 < NBUCK) ? gbase[(b + 1) * NB1] : e;
    for (int i = lo + t; i < hi; i += 1024)
        atomicAdd(&cnt[ebuf[i] & 511], 1);      // LDS atomic
    __syncthreads();
    int a = (t < 512) ? cnt[t] : 0;
    if (t < 512) ps[t] = a;
    __syncthreads();
    for (int off = 1; off < 512; off <<= 1) {
        int v = (t >= off && t < 512) ? ps[t - off] : 0;
        __syncthreads();
        if (t < 512) ps[t] += v;
        __syncthreads();
    }
    if (t < 512) {
        int g0 = lo + ps[t] - a;             // global CSR slot of node b*512+t
        int node = b * 512 + t;
        cur[t] = g0;
        if (node < n) {
            rowptr[node] = g0;
            dinv[node] = 1.0f / sqrtf((float)(a + 1));   // +1 self-loop
        }
    }
    if (b == 0 && t == 0) rowptr[n] = e;
    __syncthreads();
    for (int i = lo + t; i < hi; i += 1024) {
        int pe = ebuf[i];
        int pos = atomicAdd(&cur[pe & 511], 1);  // LDS atomic
        csrc[pos] = pe >> 9;
    }
}

// ---------------- pooling index: starts[g] = lower_bound(batch, g) ----------------
__global__ __launch_bounds__(576) void starts_kernel(const int* __restrict__ batch,
                                                     int* __restrict__ starts, int n) {
    int g = threadIdx.x;
    if (g > N_GRAPHS) return;
    int lo = 0, hi = n;
    while (lo < hi) {
        int mid = (lo + hi) >> 1;
        if (batch[mid] < g) lo = mid + 1; else hi = mid;
    }
    starts[g] = lo;
}

// ---------------- dense compute ----------------

// W[l][k][n] f32 -> WT3[l][n][k] bf16
__global__ void castWT3_kernel(const float* __restrict__ W0,
                               const float* __restrict__ W1,
                               const float* __restrict__ W2,
                               bf16* __restrict__ WT3) {
    int n = blockIdx.x, l = blockIdx.y, k = threadIdx.x;
    const float* W = (l == 0) ? W0 : (l == 1) ? W1 : W2;
    WT3[l * D * D + n * D + k] = (bf16)W[k * D + n];
}

// C[Mpad x 128] = A[Mpad x 128] @ W[128 x 128], bf16 in/out, no LDS.
__global__ __launch_bounds__(256) void gemm_kernel(const bf16* __restrict__ A,
                                                   const bf16* __restrict__ WT,
                                                   bf16* __restrict__ C) {
    int wave = threadIdx.x >> 6;
    int lane = threadIdx.x & 63;
    int m16  = lane & 15;
    int quad = lane >> 4;
    int row0 = blockIdx.x * 64 + wave * 16;

    bf16x8 a[4];
    const bf16* arow = A + (row0 + m16) * D + quad * 8;
#pragma unroll
    for (int kt = 0; kt < 4; ++kt)
        a[kt] = *(const bf16x8*)(arow + kt * 32);

#pragma unroll
    for (int nt = 0; nt < 8; ++nt) {
        f32x4 acc = {0.f, 0.f, 0.f, 0.f};
        const bf16* brow = WT + (nt * 16 + m16) * D + quad * 8;
#pragma unroll
        for (int kt = 0; kt < 4; ++kt) {
            bf16x8 b = *(const bf16x8*)(brow + kt * 32);
            acc = __builtin_amdgcn_mfma_f32_16x16x32_bf16(a[kt], b, acc, 0, 0, 0);
        }
#pragma unroll
        for (int r = 0; r < 4; ++r)
            C[(row0 + quad * 4 + r) * D + nt * 16 + m16] = (bf16)acc[r];
    }
}

// Layer-1 variant: A is f32 (the raw input x); cast to bf16 in-register.
__global__ __launch_bounds__(256) void gemm_f32_kernel(const float* __restrict__ A,
                                                       const bf16* __restrict__ WT,
                                                       bf16* __restrict__ C, int n) {
    int wave = threadIdx.x >> 6;
    int lane = threadIdx.x & 63;
    int m16  = lane & 15;
    int quad = lane >> 4;
    int row0 = blockIdx.x * 64 + wave * 16;
    int arowi = row0 + m16;

    bf16x8 a[4];
    const float* arow = A + (size_t)arowi * D + quad * 8;
#pragma unroll
    for (int kt = 0; kt < 4; ++kt) {
        float4 f0 = make_float4(0.f, 0.f, 0.f, 0.f);
        float4 f1 = make_float4(0.f, 0.f, 0.f, 0.f);
        if (arowi < n) {
            f0 = *(const float4*)(arow + kt * 32);
            f1 = *(const float4*)(arow + kt * 32 + 4);
        }
        bf16x8 v = { (bf16)f0.x, (bf16)f0.y, (bf16)f0.z, (bf16)f0.w,
                     (bf16)f1.x, (bf16)f1.y, (bf16)f1.z, (bf16)f1.w };
        a[kt] = v;
    }

#pragma unroll
    for (int nt = 0; nt < 8; ++nt) {
        f32x4 acc = {0.f, 0.f, 0.f, 0.f};
        const bf16* brow = WT + (nt * 16 + m16) * D + quad * 8;
#pragma unroll
        for (int kt = 0; kt < 4; ++kt) {
            bf16x8 b = *(const bf16x8*)(brow + kt * 32);
            acc = __builtin_amdgcn_mfma_f32_16x16x32_bf16(a[kt], b, acc, 0, 0, 0);
        }
#pragma unroll
        for (int r = 0; r < 4; ++r)
            C[(row0 + quad * 4 + r) * D + nt * 16 + m16] = (bf16)acc[r];
    }
}

// out[v][:] = relu( dinv[v]^2*h[v] + sum_e dinv[src]*dinv[v]*h[src] + bias )
// At the memory-side random-gather ceiling (R5-R10: 370MB @ 3.67TB/s) — frozen.
__global__ __launch_bounds__(256) void spmm_kernel(const bf16* __restrict__ h,
                                                   const int* __restrict__ rowptr,
                                                   const int* __restrict__ csrc,
                                                   const float* __restrict__ dinv,
                                                   const float* __restrict__ bias,
                                                   bf16* __restrict__ out, int n) {
    int v = blockIdx.x * 4 + (threadIdx.x >> 6);
    if (v >= n) return;
    int lane = threadIdx.x & 63;
    int g = lane >> 4;          // edge group 0..3
    int c = lane & 15;          // dim chunk: dims c*8 .. c*8+7
    int s = rowptr[v], e = rowptr[v + 1];
    float dv = dinv[v];

    float acc[8] = {0.f, 0.f, 0.f, 0.f, 0.f, 0.f, 0.f, 0.f};

    if (g == 0) {
        uint4 u = *(const uint4*)(h + v * D + c * 8);
        float s2 = dv * dv;
        float2 f0 = bf2f(u.x), f1 = bf2f(u.y), f2 = bf2f(u.z), f3 = bf2f(u.w);
        acc[0] = s2 * f0.x; acc[1] = s2 * f0.y;
        acc[2] = s2 * f1.x; acc[3] = s2 * f1.y;
        acc[4] = s2 * f2.x; acc[5] = s2 * f2.y;
        acc[6] = s2 * f3.x; acc[7] = s2 * f3.y;
    }

    int j = s + g;
    for (; j + 4 < e; j += 8) {
        int s0 = csrc[j], s1 = csrc[j + 4];
        float w0 = dinv[s0] * dv, w1 = dinv[s1] * dv;
        uint4 ua = *(const uint4*)(h + s0 * D + c * 8);
        uint4 ub = *(const uint4*)(h + s1 * D + c * 8);
        float2 a0 = bf2f(ua.x), a1 = bf2f(ua.y), a2 = bf2f(ua.z), a3 = bf2f(ua.w);
        float2 b0 = bf2f(ub.x), b1 = bf2f(ub.y), b2 = bf2f(ub.z), b3 = bf2f(ub.w);
        acc[0] = fmaf(w0, a0.x, acc[0]); acc[1] = fmaf(w0, a0.y, acc[1]);
        acc[2] = fmaf(w0, a1.x, acc[2]); acc[3] = fmaf(w0, a1.y, acc[3]);
        acc[4] = fmaf(w0, a2.x, acc[4]); acc[5] = fmaf(w0, a2.y, acc[5]);
        acc[6] = fmaf(w0, a3.x, acc[6]); acc[7] = fmaf(w0, a3.y, acc[7]);
        acc[0] = fmaf(w1, b0.x, acc[0]); acc[1] = fmaf(w1, b0.y, acc[1]);
        acc[2] = fmaf(w1, b1.x, acc[2]); acc[3] = fmaf(w1, b1.y, acc[3]);
        acc[4] = fmaf(w1, b2.x, acc[4]); acc[5] = fmaf(w1, b2.y, acc[5]);
        acc[6] = fmaf(w1, b3.x, acc[6]); acc[7] = fmaf(w1, b3.y, acc[7]);
    }
    if (j < e) {
        int s0 = csrc[j];
        float w0 = dinv[s0] * dv;
        uint4 ua = *(const uint4*)(h + s0 * D + c * 8);
        float2 a0 = bf2f(ua.x), a1 = bf2f(ua.y), a2 = bf2f(ua.z), a3 = bf2f(ua.w);
        acc[0] = fmaf(w0, a0.x, acc[0]); acc[1] = fmaf(w0, a0.y, acc[1]);
        acc[2] = fmaf(w0, a1.x, acc[2]); acc[3] = fmaf(w0, a1.y, acc[3]);
        acc[4] = fmaf(w0, a2.x, acc[4]); acc[5] = fmaf(w0, a2.y, acc[5]);
        acc[6] = fmaf(w0, a3.x, acc[6]); acc[7] = fmaf(w0, a3.y, acc[7]);
    }

#pragma unroll
    for (int d = 0; d < 8; ++d) {
        acc[d] += __shfl_xor(acc[d], 16);
        acc[d] += __shfl_xor(acc[d], 32);
    }

    if (g == 0) {
        float4 bi0 = *(const float4*)(bias + c * 8);
        float4 bi1 = *(const float4*)(bias + c * 8 + 4);
        bf16x8 o;
        o[0] = (bf16)fmaxf(acc[0] + bi0.x, 0.f);
        o[1] = (bf16)fmaxf(acc[1] + bi0.y, 0.f);
        o[2] = (bf16)fmaxf(acc[2] + bi0.z, 0.f);
        o[3] = (bf16)fmaxf(acc[3] + bi0.w, 0.f);
        o[4] = (bf16)fmaxf(acc[4] + bi1.x, 0.f);
        o[5] = (bf16)fmaxf(acc[5] + bi1.y, 0.f);
        o[6] = (bf16)fmaxf(acc[6] + bi1.z, 0.f);
        o[7] = (bf16)fmaxf(acc[7] + bi1.w, 0.f);
        *(bf16x8*)(out + v * D + c * 8) = o;
    }
}

// fused mean-pool + 2-layer FC head: one block per graph
__global__ __launch_bounds__(256) void poolfc_kernel(const bf16* __restrict__ h,
                                                     const int* __restrict__ starts,
                                                     const float* __restrict__ Wfc,
                                                     const float* __restrict__ bfc,
                                                     const float* __restrict__ Wfc2,
                                                     const float* __restrict__ bfc2,
                                                     float* __restrict__ out) {
    __shared__ float part[3][D];
    __shared__ float pr[D];
    __shared__ float hid[D_FF];
    int g = blockIdx.x;
    int w = threadIdx.x >> 6, lane = threadIdx.x & 63;
    int s = starts[g], e = starts[g + 1];
    float ax = 0.f, ay = 0.f;
    for (int r = s + w; r < e; r += 4) {
        unsigned u = *(const unsigned*)(h + r * D + lane * 2);
        float2 f = bf2f(u);
        ax += f.x; ay += f.y;
    }
    if (w > 0) { part[w - 1][lane * 2] = ax; part[w - 1][lane * 2 + 1] = ay; }
    __syncthreads();
    if (w == 0) {
#pragma unroll
        for (int k = 0; k < 3; ++k) { ax += part[k][lane * 2]; ay += part[k][lane * 2 + 1]; }
        float c = fmaxf((float)(e - s), 1.0f);
        pr[lane * 2]     = ax / c;
        pr[lane * 2 + 1] = ay / c;
    }
    __syncthreads();
    int t = threadIdx.x;
    float acc = bfc[t];
    for (int k = 0; k < D; ++k) acc = fmaf(pr[k], Wfc[k * D_FF + t], acc);
    hid[t] = fmaxf(acc, 0.f);
    __syncthreads();
    if (t < N_CLASSES) {
        float o = bfc2[t];
        for (int k = 0; k < D_FF; ++k) o = fmaf(hid[k], Wfc2[k * N_CLASSES + t], o);
        out[g * N_CLASSES + t] = o;
    }
}

// ---------------- launch ----------------

extern "C" void kernel_launch(void* const* d_in, const int* in_sizes, int n_in,
                              void* d_out, int out_size, void* d_ws, size_t ws_size,
                              hipStream_t stream) {
    const float* x     = (const float*)d_in[0];
    const int*   eidx  = (const int*)d_in[1];
    const int*   batch = (const int*)d_in[2];
    const float* W[3]  = { (const float*)d_in[3], (const float*)d_in[5], (const float*)d_in[7] };
    const float* b[3]  = { (const float*)d_in[4], (const float*)d_in[6], (const float*)d_in[8] };
    const float* Wfc   = (const float*)d_in[9];
    const float* bfc   = (const float*)d_in[10];
    const float* Wfc2  = (const float*)d_in[11];
    const float* bfc2  = (const float*)d_in[12];
    float* out = (float*)d_out;

    const int E = in_sizes[1] / 2;           // 3,200,000
    const int N = in_sizes[0] / D;           // 100,000
    const int* esrc = eidx;
    const int* edst = eidx + E;

    uint8_t* base = (uint8_t*)d_ws;
    size_t off = 0;
    auto alloc = [&](size_t bytes) -> void* {
        void* p = base + off;
        off = (off + bytes + 255) & ~(size_t)255;
        return p;
    };
    bf16*  hA     = (bf16*) alloc((size_t)N_PAD * D * 2);
    bf16*  hB     = (bf16*) alloc((size_t)N_PAD * D * 2);
    bf16*  WT3    = (bf16*) alloc((size_t)3 * D * D * 2);
    int*   csrc   = (int*)  alloc((size_t)E * 4);
    int*   ebuf   = (int*)  alloc((size_t)E * 4);
    int*   gcount = (int*)  alloc((size_t)NBUCK * NB1 * 4);
    int*   gbase  = (int*)  alloc((size_t)(NBUCK * NB1 + 1) * 4);
    int*   rowptr = (int*)  alloc((size_t)(N + 1) * 4);
    float* dinv   = (float*)alloc((size_t)N * 4);
    int*   bsum   = (int*)  alloc(4096);
    int*   boff   = (int*)  alloc(4096);
    int*   starts = (int*)  alloc((size_t)(N_GRAPHS + 1) * 4);
    (void)ws_size; (void)n_in; (void)out_size;

    const int GB  = N_PAD / 64;                         // 1563
    const int SB  = (N + 3) / 4;                        // spmm blocks
    const int GCN = NBUCK * NB1;                        // 200704
    const int GCB = (GCN + 255) / 256;                  // 784

    // CSR build (atomic-free, LDS counting sort)
    p1_hist<<<NB1, 256, 0, stream>>>(edst, gcount, E);
    scan1<<<GCB, 256, 0, stream>>>(gcount, gbase, bsum, GCN);
    scan2<<<1, 1024, 0, stream>>>(bsum, boff, GCB);
    scan3<<<GCB, 256, 0, stream>>>(gbase, boff, GCN);
    p3_scatter<<<NB1, 256, 0, stream>>>(esrc, edst, gbase, ebuf, E);
    p45_fill<<<NBUCK, 1024, 0, stream>>>(ebuf, gbase, dinv, rowptr, csrc, E, N);

    // pooling segments: parallel binary search
    starts_kernel<<<1, 576, 0, stream>>>(batch, starts, N);

    // weights for all 3 layers
    castWT3_kernel<<<dim3(D, 3), D, 0, stream>>>(W[0], W[1], W[2], WT3);

    // layer 1 (f32 input, in-register cast), then layers 2-3
    gemm_f32_kernel<<<GB, 256, 0, stream>>>(x, WT3, hA, N);
    spmm_kernel<<<SB, 256, 0, stream>>>(hA, rowptr, csrc, dinv, b[0], hB, N);
    for (int l = 1; l < 3; ++l) {
        gemm_kernel<<<GB, 256, 0, stream>>>(hB, WT3 + (size_t)l * D * D, hA);
        spmm_kernel<<<SB, 256, 0, stream>>>(hA, rowptr, csrc, dinv, b[l], hB, N);
    }

    // fused mean-pool + FC head
    poolfc_kernel<<<N_GRAPHS, 256, 0, stream>>>(hB, starts, Wfc, bfc, Wfc2, bfc2, out);
}

// Round 12
// 645.004 us; speedup vs baseline: 1.1150x; 1.0339x over previous
//
#include <hip/hip_runtime.h>
#include <hip/hip_bf16.h>

typedef __bf16 bf16;
typedef __attribute__((ext_vector_type(8))) __bf16 bf16x8;
typedef __attribute__((ext_vector_type(4))) float f32x4;

constexpr int N_NODES   = 100000;
constexpr int N_PAD     = 100032;   // multiple of 64 (GEMM block tile)
constexpr int D         = 128;
constexpr int D_FF      = 256;
constexpr int N_CLASSES = 26;
constexpr int N_GRAPHS  = 512;
constexpr int NB1       = 1024;                      // partition blocks
constexpr int NBUCK     = (N_NODES + 511) / 512;     // 196 dst-buckets of 512 nodes

__device__ inline float2 bf2f(unsigned u) {
    float lo = __uint_as_float(u << 16);
    float hi = __uint_as_float(u & 0xffff0000u);
    return make_float2(lo, hi);
}

// ---------------- CSR build: atomic-free bucket counting sort ----------------

// P1: per-block LDS histogram over dst buckets (bucket = dst >> 9)
// 512 threads (R12): same occupancy lever as R11's p45 — LDS-atomic edge-pass
// kernels are issue/latency-bound, 8 waves/block fills the chip exactly.
__global__ __launch_bounds__(512) void p1_hist(const int* __restrict__ edst,
                                               int* __restrict__ gcount, int e) {
    __shared__ int cnt[NBUCK];
    for (int t = threadIdx.x; t < NBUCK; t += 512) cnt[t] = 0;
    __syncthreads();
    int chunk = (e + NB1 - 1) / NB1;
    int lo = blockIdx.x * chunk;
    int hi = min(e, lo + chunk);
    for (int i = lo + threadIdx.x; i < hi; i += 512)
        atomicAdd(&cnt[edst[i] >> 9], 1);
    __syncthreads();
    for (int t = threadIdx.x; t < NBUCK; t += 512)
        gcount[t * NB1 + blockIdx.x] = cnt[t];
}

// 3-phase exclusive scan: out[0]=0, out[i+1]=incl[i] (+ block offsets)
__global__ __launch_bounds__(256) void scan1(const int* __restrict__ in,
                                             int* out, int* bsum, int n) {
    __shared__ int sd[256];
    int i = blockIdx.x * 256 + threadIdx.x;
    int v = (i < n) ? in[i] : 0;
    sd[threadIdx.x] = v; __syncthreads();
    for (int off = 1; off < 256; off <<= 1) {
        int t = (threadIdx.x >= off) ? sd[threadIdx.x - off] : 0;
        __syncthreads();
        sd[threadIdx.x] += t;
        __syncthreads();
    }
    if (i < n) out[i + 1] = sd[threadIdx.x];
    if (threadIdx.x == 255) bsum[blockIdx.x] = sd[255];
}

__global__ __launch_bounds__(1024) void scan2(const int* __restrict__ bsum,
                                              int* boff, int nb) {
    __shared__ int sd[1024];
    int t = threadIdx.x;
    int v = (t < nb) ? bsum[t] : 0;
    sd[t] = v; __syncthreads();
    for (int off = 1; off < 1024; off <<= 1) {
        int x = (t >= off) ? sd[t - off] : 0;
        __syncthreads();
        sd[t] += x;
        __syncthreads();
    }
    if (t < nb) boff[t] = sd[t] - v;  // exclusive
}

__global__ void scan3(int* out, const int* __restrict__ boff, int n) {
    int i = blockIdx.x * 256 + threadIdx.x;
    if (i < n) out[i + 1] += boff[blockIdx.x];
    if (i == 0) out[0] = 0;
}

// P3: scatter edges into bucket-contiguous ebuf; pack (src<<9)|(dst&511)
// 512 threads (R12): same lever; 1024 blocks x 8 waves = full wave capacity.
__global__ __launch_bounds__(512) void p3_scatter(const int* __restrict__ esrc,
                                                  const int* __restrict__ edst,
                                                  const int* __restrict__ gbase,
                                                  int* __restrict__ ebuf, int e) {
    __shared__ int cur[NBUCK];
    for (int t = threadIdx.x; t < NBUCK; t += 512)
        cur[t] = gbase[t * NB1 + blockIdx.x];
    __syncthreads();
    int chunk = (e + NB1 - 1) / NB1;
    int lo = blockIdx.x * chunk;
    int hi = min(e, lo + chunk);
    for (int i = lo + threadIdx.x; i < hi; i += 512) {
        int d = edst[i], s = esrc[i];
        int pos = atomicAdd(&cur[d >> 9], 1);   // LDS atomic
        ebuf[pos] = (s << 9) | (d & 511);
    }
}

// P45: fused per-bucket degree count + LDS scan + CSR fill (1024 thr, R11)
__global__ __launch_bounds__(1024) void p45_fill(const int* __restrict__ ebuf,
                                                 const int* __restrict__ gbase,
                                                 float* __restrict__ dinv,
                                                 int* __restrict__ rowptr,
                                                 int* __restrict__ csrc, int e, int n) {
    __shared__ int cnt[512];
    __shared__ int ps[512];
    __shared__ int cur[512];
    int b = blockIdx.x, t = threadIdx.x;
    if (t < 512) cnt[t] = 0;
    __syncthreads();
    int lo = gbase[b * NB1];
    int hi = (b + 1 < NBUCK) ? gbase[(b + 1) * NB1] : e;
    for (int i = lo + t; i < hi; i += 1024)
        atomicAdd(&cnt[ebuf[i] & 511], 1);      // LDS atomic
    __syncthreads();
    int a = (t < 512) ? cnt[t] : 0;
    if (t < 512) ps[t] = a;
    __syncthreads();
    for (int off = 1; off < 512; off <<= 1) {
        int v = (t >= off && t < 512) ? ps[t - off] : 0;
        __syncthreads();
        if (t < 512) ps[t] += v;
        __syncthreads();
    }
    if (t < 512) {
        int g0 = lo + ps[t] - a;             // global CSR slot of node b*512+t
        int node = b * 512 + t;
        cur[t] = g0;
        if (node < n) {
            rowptr[node] = g0;
            dinv[node] = 1.0f / sqrtf((float)(a + 1));   // +1 self-loop
        }
    }
    if (b == 0 && t == 0) rowptr[n] = e;
    __syncthreads();
    for (int i = lo + t; i < hi; i += 1024) {
        int pe = ebuf[i];
        int pos = atomicAdd(&cur[pe & 511], 1);  // LDS atomic
        csrc[pos] = pe >> 9;
    }
}

// ---------------- pooling index: starts[g] = lower_bound(batch, g) ----------------
__global__ __launch_bounds__(576) void starts_kernel(const int* __restrict__ batch,
                                                     int* __restrict__ starts, int n) {
    int g = threadIdx.x;
    if (g > N_GRAPHS) return;
    int lo = 0, hi = n;
    while (lo < hi) {
        int mid = (lo + hi) >> 1;
        if (batch[mid] < g) lo = mid + 1; else hi = mid;
    }
    starts[g] = lo;
}

// ---------------- dense compute ----------------

// W[l][k][n] f32 -> WT3[l][n][k] bf16
__global__ void castWT3_kernel(const float* __restrict__ W0,
                               const float* __restrict__ W1,
                               const float* __restrict__ W2,
                               bf16* __restrict__ WT3) {
    int n = blockIdx.x, l = blockIdx.y, k = threadIdx.x;
    const float* W = (l == 0) ? W0 : (l == 1) ? W1 : W2;
    WT3[l * D * D + n * D + k] = (bf16)W[k * D + n];
}

// C[Mpad x 128] = A[Mpad x 128] @ W[128 x 128], bf16 in/out, no LDS.
__global__ __launch_bounds__(256) void gemm_kernel(const bf16* __restrict__ A,
                                                   const bf16* __restrict__ WT,
                                                   bf16* __restrict__ C) {
    int wave = threadIdx.x >> 6;
    int lane = threadIdx.x & 63;
    int m16  = lane & 15;
    int quad = lane >> 4;
    int row0 = blockIdx.x * 64 + wave * 16;

    bf16x8 a[4];
    const bf16* arow = A + (row0 + m16) * D + quad * 8;
#pragma unroll
    for (int kt = 0; kt < 4; ++kt)
        a[kt] = *(const bf16x8*)(arow + kt * 32);

#pragma unroll
    for (int nt = 0; nt < 8; ++nt) {
        f32x4 acc = {0.f, 0.f, 0.f, 0.f};
        const bf16* brow = WT + (nt * 16 + m16) * D + quad * 8;
#pragma unroll
        for (int kt = 0; kt < 4; ++kt) {
            bf16x8 b = *(const bf16x8*)(brow + kt * 32);
            acc = __builtin_amdgcn_mfma_f32_16x16x32_bf16(a[kt], b, acc, 0, 0, 0);
        }
#pragma unroll
        for (int r = 0; r < 4; ++r)
            C[(row0 + quad * 4 + r) * D + nt * 16 + m16] = (bf16)acc[r];
    }
}

// Layer-1 variant: A is f32 (the raw input x); cast to bf16 in-register.
__global__ __launch_bounds__(256) void gemm_f32_kernel(const float* __restrict__ A,
                                                       const bf16* __restrict__ WT,
                                                       bf16* __restrict__ C, int n) {
    int wave = threadIdx.x >> 6;
    int lane = threadIdx.x & 63;
    int m16  = lane & 15;
    int quad = lane >> 4;
    int row0 = blockIdx.x * 64 + wave * 16;
    int arowi = row0 + m16;

    bf16x8 a[4];
    const float* arow = A + (size_t)arowi * D + quad * 8;
#pragma unroll
    for (int kt = 0; kt < 4; ++kt) {
        float4 f0 = make_float4(0.f, 0.f, 0.f, 0.f);
        float4 f1 = make_float4(0.f, 0.f, 0.f, 0.f);
        if (arowi < n) {
            f0 = *(const float4*)(arow + kt * 32);
            f1 = *(const float4*)(arow + kt * 32 + 4);
        }
        bf16x8 v = { (bf16)f0.x, (bf16)f0.y, (bf16)f0.z, (bf16)f0.w,
                     (bf16)f1.x, (bf16)f1.y, (bf16)f1.z, (bf16)f1.w };
        a[kt] = v;
    }

#pragma unroll
    for (int nt = 0; nt < 8; ++nt) {
        f32x4 acc = {0.f, 0.f, 0.f, 0.f};
        const bf16* brow = WT + (nt * 16 + m16) * D + quad * 8;
#pragma unroll
        for (int kt = 0; kt < 4; ++kt) {
            bf16x8 b = *(const bf16x8*)(brow + kt * 32);
            acc = __builtin_amdgcn_mfma_f32_16x16x32_bf16(a[kt], b, acc, 0, 0, 0);
        }
#pragma unroll
        for (int r = 0; r < 4; ++r)
            C[(row0 + quad * 4 + r) * D + nt * 16 + m16] = (bf16)acc[r];
    }
}

// out[v][:] = relu( dinv[v]^2*h[v] + sum_e dinv[src]*dinv[v]*h[src] + bias )
// At the memory-side random-gather ceiling (R5-R11: 370MB @ 3.67TB/s) — frozen.
__global__ __launch_bounds__(256) void spmm_kernel(const bf16* __restrict__ h,
                                                   const int* __restrict__ rowptr,
                                                   const int* __restrict__ csrc,
                                                   const float* __restrict__ dinv,
                                                   const float* __restrict__ bias,
                                                   bf16* __restrict__ out, int n) {
    int v = blockIdx.x * 4 + (threadIdx.x >> 6);
    if (v >= n) return;
    int lane = threadIdx.x & 63;
    int g = lane >> 4;          // edge group 0..3
    int c = lane & 15;          // dim chunk: dims c*8 .. c*8+7
    int s = rowptr[v], e = rowptr[v + 1];
    float dv = dinv[v];

    float acc[8] = {0.f, 0.f, 0.f, 0.f, 0.f, 0.f, 0.f, 0.f};

    if (g == 0) {
        uint4 u = *(const uint4*)(h + v * D + c * 8);
        float s2 = dv * dv;
        float2 f0 = bf2f(u.x), f1 = bf2f(u.y), f2 = bf2f(u.z), f3 = bf2f(u.w);
        acc[0] = s2 * f0.x; acc[1] = s2 * f0.y;
        acc[2] = s2 * f1.x; acc[3] = s2 * f1.y;
        acc[4] = s2 * f2.x; acc[5] = s2 * f2.y;
        acc[6] = s2 * f3.x; acc[7] = s2 * f3.y;
    }

    int j = s + g;
    for (; j + 4 < e; j += 8) {
        int s0 = csrc[j], s1 = csrc[j + 4];
        float w0 = dinv[s0] * dv, w1 = dinv[s1] * dv;
        uint4 ua = *(const uint4*)(h + s0 * D + c * 8);
        uint4 ub = *(const uint4*)(h + s1 * D + c * 8);
        float2 a0 = bf2f(ua.x), a1 = bf2f(ua.y), a2 = bf2f(ua.z), a3 = bf2f(ua.w);
        float2 b0 = bf2f(ub.x), b1 = bf2f(ub.y), b2 = bf2f(ub.z), b3 = bf2f(ub.w);
        acc[0] = fmaf(w0, a0.x, acc[0]); acc[1] = fmaf(w0, a0.y, acc[1]);
        acc[2] = fmaf(w0, a1.x, acc[2]); acc[3] = fmaf(w0, a1.y, acc[3]);
        acc[4] = fmaf(w0, a2.x, acc[4]); acc[5] = fmaf(w0, a2.y, acc[5]);
        acc[6] = fmaf(w0, a3.x, acc[6]); acc[7] = fmaf(w0, a3.y, acc[7]);
        acc[0] = fmaf(w1, b0.x, acc[0]); acc[1] = fmaf(w1, b0.y, acc[1]);
        acc[2] = fmaf(w1, b1.x, acc[2]); acc[3] = fmaf(w1, b1.y, acc[3]);
        acc[4] = fmaf(w1, b2.x, acc[4]); acc[5] = fmaf(w1, b2.y, acc[5]);
        acc[6] = fmaf(w1, b3.x, acc[6]); acc[7] = fmaf(w1, b3.y, acc[7]);
    }
    if (j < e) {
        int s0 = csrc[j];
        float w0 = dinv[s0] * dv;
        uint4 ua = *(const uint4*)(h + s0 * D + c * 8);
        float2 a0 = bf2f(ua.x), a1 = bf2f(ua.y), a2 = bf2f(ua.z), a3 = bf2f(ua.w);
        acc[0] = fmaf(w0, a0.x, acc[0]); acc[1] = fmaf(w0, a0.y, acc[1]);
        acc[2] = fmaf(w0, a1.x, acc[2]); acc[3] = fmaf(w0, a1.y, acc[3]);
        acc[4] = fmaf(w0, a2.x, acc[4]); acc[5] = fmaf(w0, a2.y, acc[5]);
        acc[6] = fmaf(w0, a3.x, acc[6]); acc[7] = fmaf(w0, a3.y, acc[7]);
    }

#pragma unroll
    for (int d = 0; d < 8; ++d) {
        acc[d] += __shfl_xor(acc[d], 16);
        acc[d] += __shfl_xor(acc[d], 32);
    }

    if (g == 0) {
        float4 bi0 = *(const float4*)(bias + c * 8);
        float4 bi1 = *(const float4*)(bias + c * 8 + 4);
        bf16x8 o;
        o[0] = (bf16)fmaxf(acc[0] + bi0.x, 0.f);
        o[1] = (bf16)fmaxf(acc[1] + bi0.y, 0.f);
        o[2] = (bf16)fmaxf(acc[2] + bi0.z, 0.f);
        o[3] = (bf16)fmaxf(acc[3] + bi0.w, 0.f);
        o[4] = (bf16)fmaxf(acc[4] + bi1.x, 0.f);
        o[5] = (bf16)fmaxf(acc[5] + bi1.y, 0.f);
        o[6] = (bf16)fmaxf(acc[6] + bi1.z, 0.f);
        o[7] = (bf16)fmaxf(acc[7] + bi1.w, 0.f);
        *(bf16x8*)(out + v * D + c * 8) = o;
    }
}

// fused mean-pool + 2-layer FC head: one block per graph
__global__ __launch_bounds__(256) void poolfc_kernel(const bf16* __restrict__ h,
                                                     const int* __restrict__ starts,
                                                     const float* __restrict__ Wfc,
                                                     const float* __restrict__ bfc,
                                                     const float* __restrict__ Wfc2,
                                                     const float* __restrict__ bfc2,
                                                     float* __restrict__ out) {
    __shared__ float part[3][D];
    __shared__ float pr[D];
    __shared__ float hid[D_FF];
    int g = blockIdx.x;
    int w = threadIdx.x >> 6, lane = threadIdx.x & 63;
    int s = starts[g], e = starts[g + 1];
    float ax = 0.f, ay = 0.f;
    for (int r = s + w; r < e; r += 4) {
        unsigned u = *(const unsigned*)(h + r * D + lane * 2);
        float2 f = bf2f(u);
        ax += f.x; ay += f.y;
    }
    if (w > 0) { part[w - 1][lane * 2] = ax; part[w - 1][lane * 2 + 1] = ay; }
    __syncthreads();
    if (w == 0) {
#pragma unroll
        for (int k = 0; k < 3; ++k) { ax += part[k][lane * 2]; ay += part[k][lane * 2 + 1]; }
        float c = fmaxf((float)(e - s), 1.0f);
        pr[lane * 2]     = ax / c;
        pr[lane * 2 + 1] = ay / c;
    }
    __syncthreads();
    int t = threadIdx.x;
    float acc = bfc[t];
    for (int k = 0; k < D; ++k) acc = fmaf(pr[k], Wfc[k * D_FF + t], acc);
    hid[t] = fmaxf(acc, 0.f);
    __syncthreads();
    if (t < N_CLASSES) {
        float o = bfc2[t];
        for (int k = 0; k < D_FF; ++k) o = fmaf(hid[k], Wfc2[k * N_CLASSES + t], o);
        out[g * N_CLASSES + t] = o;
    }
}

// ---------------- launch ----------------

extern "C" void kernel_launch(void* const* d_in, const int* in_sizes, int n_in,
                              void* d_out, int out_size, void* d_ws, size_t ws_size,
                              hipStream_t stream) {
    const float* x     = (const float*)d_in[0];
    const int*   eidx  = (const int*)d_in[1];
    const int*   batch = (const int*)d_in[2];
    const float* W[3]  = { (const float*)d_in[3], (const float*)d_in[5], (const float*)d_in[7] };
    const float* b[3]  = { (const float*)d_in[4], (const float*)d_in[6], (const float*)d_in[8] };
    const float* Wfc   = (const float*)d_in[9];
    const float* bfc   = (const float*)d_in[10];
    const float* Wfc2  = (const float*)d_in[11];
    const float* bfc2  = (const float*)d_in[12];
    float* out = (float*)d_out;

    const int E = in_sizes[1] / 2;           // 3,200,000
    const int N = in_sizes[0] / D;           // 100,000
    const int* esrc = eidx;
    const int* edst = eidx + E;

    uint8_t* base = (uint8_t*)d_ws;
    size_t off = 0;
    auto alloc = [&](size_t bytes) -> void* {
        void* p = base + off;
        off = (off + bytes + 255) & ~(size_t)255;
        return p;
    };
    bf16*  hA     = (bf16*) alloc((size_t)N_PAD * D * 2);
    bf16*  hB     = (bf16*) alloc((size_t)N_PAD * D * 2);
    bf16*  WT3    = (bf16*) alloc((size_t)3 * D * D * 2);
    int*   csrc   = (int*)  alloc((size_t)E * 4);
    int*   ebuf   = (int*)  alloc((size_t)E * 4);
    int*   gcount = (int*)  alloc((size_t)NBUCK * NB1 * 4);
    int*   gbase  = (int*)  alloc((size_t)(NBUCK * NB1 + 1) * 4);
    int*   rowptr = (int*)  alloc((size_t)(N + 1) * 4);
    float* dinv   = (float*)alloc((size_t)N * 4);
    int*   bsum   = (int*)  alloc(4096);
    int*   boff   = (int*)  alloc(4096);
    int*   starts = (int*)  alloc((size_t)(N_GRAPHS + 1) * 4);
    (void)ws_size; (void)n_in; (void)out_size;

    const int GB  = N_PAD / 64;                         // 1563
    const int SB  = (N + 3) / 4;                        // spmm blocks
    const int GCN = NBUCK * NB1;                        // 200704
    const int GCB = (GCN + 255) / 256;                  // 784

    // CSR build (atomic-free, LDS counting sort)
    p1_hist<<<NB1, 512, 0, stream>>>(edst, gcount, E);
    scan1<<<GCB, 256, 0, stream>>>(gcount, gbase, bsum, GCN);
    scan2<<<1, 1024, 0, stream>>>(bsum, boff, GCB);
    scan3<<<GCB, 256, 0, stream>>>(gbase, boff, GCN);
    p3_scatter<<<NB1, 512, 0, stream>>>(esrc, edst, gbase, ebuf, E);
    p45_fill<<<NBUCK, 1024, 0, stream>>>(ebuf, gbase, dinv, rowptr, csrc, E, N);

    // pooling segments: parallel binary search
    starts_kernel<<<1, 576, 0, stream>>>(batch, starts, N);

    // weights for all 3 layers
    castWT3_kernel<<<dim3(D, 3), D, 0, stream>>>(W[0], W[1], W[2], WT3);

    // layer 1 (f32 input, in-register cast), then layers 2-3
    gemm_f32_kernel<<<GB, 256, 0, stream>>>(x, WT3, hA, N);
    spmm_kernel<<<SB, 256, 0, stream>>>(hA, rowptr, csrc, dinv, b[0], hB, N);
    for (int l = 1; l < 3; ++l) {
        gemm_kernel<<<GB, 256, 0, stream>>>(hB, WT3 + (size_t)l * D * D, hA);
        spmm_kernel<<<SB, 256, 0, stream>>>(hA, rowptr, csrc, dinv, b[l], hB, N);
    }

    // fused mean-pool + FC head
    poolfc_kernel<<<N_GRAPHS, 256, 0, stream>>>(hB, starts, Wfc, bfc, Wfc2, bfc2, out);
}

// Round 13
// 636.408 us; speedup vs baseline: 1.1301x; 1.0135x over previous
//
#include <hip/hip_runtime.h>
#include <hip/hip_bf16.h>

typedef __bf16 bf16;
typedef __attribute__((ext_vector_type(8))) __bf16 bf16x8;
typedef __attribute__((ext_vector_type(4))) float f32x4;

constexpr int N_NODES   = 100000;
constexpr int N_PAD     = 100032;   // multiple of 64 (GEMM block tile)
constexpr int D         = 128;
constexpr int D_FF      = 256;
constexpr int N_CLASSES = 26;
constexpr int N_GRAPHS  = 512;
// R13: NB1 1024->256. 1024 blocks x 196 bucket-cursors = 200k concurrent
// partial-line write streams (12.8MB) -> L2 evicts partials before they fill
// (write amplification). 256 blocks -> 400KB/XCD of cursors, L2-resident.
// Thread count 1024 keeps 4096 waves (R9's 2048-wave config was the regression).
constexpr int NB1       = 256;                       // partition blocks
constexpr int NBUCK     = (N_NODES + 511) / 512;     // 196 dst-buckets of 512 nodes

__device__ inline float2 bf2f(unsigned u) {
    float lo = __uint_as_float(u << 16);
    float hi = __uint_as_float(u & 0xffff0000u);
    return make_float2(lo, hi);
}

// ---------------- CSR build: atomic-free bucket counting sort ----------------

// P1: per-block LDS histogram over dst buckets (bucket = dst >> 9)
__global__ __launch_bounds__(1024) void p1_hist(const int* __restrict__ edst,
                                                int* __restrict__ gcount, int e) {
    __shared__ int cnt[NBUCK];
    for (int t = threadIdx.x; t < NBUCK; t += 1024) cnt[t] = 0;
    __syncthreads();
    int chunk = (e + NB1 - 1) / NB1;
    int lo = blockIdx.x * chunk;
    int hi = min(e, lo + chunk);
    for (int i = lo + threadIdx.x; i < hi; i += 1024)
        atomicAdd(&cnt[edst[i] >> 9], 1);
    __syncthreads();
    for (int t = threadIdx.x; t < NBUCK; t += 1024)
        gcount[t * NB1 + blockIdx.x] = cnt[t];
}

// 3-phase exclusive scan: out[0]=0, out[i+1]=incl[i] (+ block offsets)
__global__ __launch_bounds__(256) void scan1(const int* __restrict__ in,
                                             int* out, int* bsum, int n) {
    __shared__ int sd[256];
    int i = blockIdx.x * 256 + threadIdx.x;
    int v = (i < n) ? in[i] : 0;
    sd[threadIdx.x] = v; __syncthreads();
    for (int off = 1; off < 256; off <<= 1) {
        int t = (threadIdx.x >= off) ? sd[threadIdx.x - off] : 0;
        __syncthreads();
        sd[threadIdx.x] += t;
        __syncthreads();
    }
    if (i < n) out[i + 1] = sd[threadIdx.x];
    if (threadIdx.x == 255) bsum[blockIdx.x] = sd[255];
}

__global__ __launch_bounds__(1024) void scan2(const int* __restrict__ bsum,
                                              int* boff, int nb) {
    __shared__ int sd[1024];
    int t = threadIdx.x;
    int v = (t < nb) ? bsum[t] : 0;
    sd[t] = v; __syncthreads();
    for (int off = 1; off < 1024; off <<= 1) {
        int x = (t >= off) ? sd[t - off] : 0;
        __syncthreads();
        sd[t] += x;
        __syncthreads();
    }
    if (t < nb) boff[t] = sd[t] - v;  // exclusive
}

__global__ void scan3(int* out, const int* __restrict__ boff, int n) {
    int i = blockIdx.x * 256 + threadIdx.x;
    if (i < n) out[i + 1] += boff[blockIdx.x];
    if (i == 0) out[0] = 0;
}

// P3: scatter edges into bucket-contiguous ebuf; pack (src<<9)|(dst&511)
__global__ __launch_bounds__(1024) void p3_scatter(const int* __restrict__ esrc,
                                                   const int* __restrict__ edst,
                                                   const int* __restrict__ gbase,
                                                   int* __restrict__ ebuf, int e) {
    __shared__ int cur[NBUCK];
    for (int t = threadIdx.x; t < NBUCK; t += 1024)
        cur[t] = gbase[t * NB1 + blockIdx.x];
    __syncthreads();
    int chunk = (e + NB1 - 1) / NB1;
    int lo = blockIdx.x * chunk;
    int hi = min(e, lo + chunk);
    for (int i = lo + threadIdx.x; i < hi; i += 1024) {
        int d = edst[i], s = esrc[i];
        int pos = atomicAdd(&cur[d >> 9], 1);   // LDS atomic
        ebuf[pos] = (s << 9) | (d & 511);
    }
}

// P45: fused per-bucket degree count + LDS scan + CSR fill (1024 thr, R11)
__global__ __launch_bounds__(1024) void p45_fill(const int* __restrict__ ebuf,
                                                 const int* __restrict__ gbase,
                                                 float* __restrict__ dinv,
                                                 int* __restrict__ rowptr,
                                                 int* __restrict__ csrc, int e, int n) {
    __shared__ int cnt[512];
    __shared__ int ps[512];
    __shared__ int cur[512];
    int b = blockIdx.x, t = threadIdx.x;
    if (t < 512) cnt[t] = 0;
    __syncthreads();
    int lo = gbase[b * NB1];
    int hi = (b + 1 < NBUCK) ? gbase[(b + 1) * NB1] : e;
    for (int i = lo + t; i < hi; i += 1024)
        atomicAdd(&cnt[ebuf[i] & 511], 1);      // LDS atomic
    __syncthreads();
    int a = (t < 512) ? cnt[t] : 0;
    if (t < 512) ps[t] = a;
    __syncthreads();
    for (int off = 1; off < 512; off <<= 1) {
        int v = (t >= off && t < 512) ? ps[t - off] : 0;
        __syncthreads();
        if (t < 512) ps[t] += v;
        __syncthreads();
    }
    if (t < 512) {
        int g0 = lo + ps[t] - a;             // global CSR slot of node b*512+t
        int node = b * 512 + t;
        cur[t] = g0;
        if (node < n) {
            rowptr[node] = g0;
            dinv[node] = 1.0f / sqrtf((float)(a + 1));   // +1 self-loop
        }
    }
    if (b == 0 && t == 0) rowptr[n] = e;
    __syncthreads();
    for (int i = lo + t; i < hi; i += 1024) {
        int pe = ebuf[i];
        int pos = atomicAdd(&cur[pe & 511], 1);  // LDS atomic
        csrc[pos] = pe >> 9;
    }
}

// ---------------- pooling index: starts[g] = lower_bound(batch, g) ----------------
__global__ __launch_bounds__(576) void starts_kernel(const int* __restrict__ batch,
                                                     int* __restrict__ starts, int n) {
    int g = threadIdx.x;
    if (g > N_GRAPHS) return;
    int lo = 0, hi = n;
    while (lo < hi) {
        int mid = (lo + hi) >> 1;
        if (batch[mid] < g) lo = mid + 1; else hi = mid;
    }
    starts[g] = lo;
}

// ---------------- dense compute ----------------

// W[l][k][n] f32 -> WT3[l][n][k] bf16
__global__ void castWT3_kernel(const float* __restrict__ W0,
                               const float* __restrict__ W1,
                               const float* __restrict__ W2,
                               bf16* __restrict__ WT3) {
    int n = blockIdx.x, l = blockIdx.y, k = threadIdx.x;
    const float* W = (l == 0) ? W0 : (l == 1) ? W1 : W2;
    WT3[l * D * D + n * D + k] = (bf16)W[k * D + n];
}

// C[Mpad x 128] = A[Mpad x 128] @ W[128 x 128], bf16 in/out, no LDS.
__global__ __launch_bounds__(256) void gemm_kernel(const bf16* __restrict__ A,
                                                   const bf16* __restrict__ WT,
                                                   bf16* __restrict__ C) {
    int wave = threadIdx.x >> 6;
    int lane = threadIdx.x & 63;
    int m16  = lane & 15;
    int quad = lane >> 4;
    int row0 = blockIdx.x * 64 + wave * 16;

    bf16x8 a[4];
    const bf16* arow = A + (row0 + m16) * D + quad * 8;
#pragma unroll
    for (int kt = 0; kt < 4; ++kt)
        a[kt] = *(const bf16x8*)(arow + kt * 32);

#pragma unroll
    for (int nt = 0; nt < 8; ++nt) {
        f32x4 acc = {0.f, 0.f, 0.f, 0.f};
        const bf16* brow = WT + (nt * 16 + m16) * D + quad * 8;
#pragma unroll
        for (int kt = 0; kt < 4; ++kt) {
            bf16x8 b = *(const bf16x8*)(brow + kt * 32);
            acc = __builtin_amdgcn_mfma_f32_16x16x32_bf16(a[kt], b, acc, 0, 0, 0);
        }
#pragma unroll
        for (int r = 0; r < 4; ++r)
            C[(row0 + quad * 4 + r) * D + nt * 16 + m16] = (bf16)acc[r];
    }
}

// Layer-1 variant: A is f32 (the raw input x); cast to bf16 in-register.
__global__ __launch_bounds__(256) void gemm_f32_kernel(const float* __restrict__ A,
                                                       const bf16* __restrict__ WT,
                                                       bf16* __restrict__ C, int n) {
    int wave = threadIdx.x >> 6;
    int lane = threadIdx.x & 63;
    int m16  = lane & 15;
    int quad = lane >> 4;
    int row0 = blockIdx.x * 64 + wave * 16;
    int arowi = row0 + m16;

    bf16x8 a[4];
    const float* arow = A + (size_t)arowi * D + quad * 8;
#pragma unroll
    for (int kt = 0; kt < 4; ++kt) {
        float4 f0 = make_float4(0.f, 0.f, 0.f, 0.f);
        float4 f1 = make_float4(0.f, 0.f, 0.f, 0.f);
        if (arowi < n) {
            f0 = *(const float4*)(arow + kt * 32);
            f1 = *(const float4*)(arow + kt * 32 + 4);
        }
        bf16x8 v = { (bf16)f0.x, (bf16)f0.y, (bf16)f0.z, (bf16)f0.w,
                     (bf16)f1.x, (bf16)f1.y, (bf16)f1.z, (bf16)f1.w };
        a[kt] = v;
    }

#pragma unroll
    for (int nt = 0; nt < 8; ++nt) {
        f32x4 acc = {0.f, 0.f, 0.f, 0.f};
        const bf16* brow = WT + (nt * 16 + m16) * D + quad * 8;
#pragma unroll
        for (int kt = 0; kt < 4; ++kt) {
            bf16x8 b = *(const bf16x8*)(brow + kt * 32);
            acc = __builtin_amdgcn_mfma_f32_16x16x32_bf16(a[kt], b, acc, 0, 0, 0);
        }
#pragma unroll
        for (int r = 0; r < 4; ++r)
            C[(row0 + quad * 4 + r) * D + nt * 16 + m16] = (bf16)acc[r];
    }
}

// out[v][:] = relu( dinv[v]^2*h[v] + sum_e dinv[src]*dinv[v]*h[src] + bias )
// At the memory-side random-gather ceiling (R5-R12: 370MB @ 3.67TB/s) — frozen.
__global__ __launch_bounds__(256) void spmm_kernel(const bf16* __restrict__ h,
                                                   const int* __restrict__ rowptr,
                                                   const int* __restrict__ csrc,
                                                   const float* __restrict__ dinv,
                                                   const float* __restrict__ bias,
                                                   bf16* __restrict__ out, int n) {
    int v = blockIdx.x * 4 + (threadIdx.x >> 6);
    if (v >= n) return;
    int lane = threadIdx.x & 63;
    int g = lane >> 4;          // edge group 0..3
    int c = lane & 15;          // dim chunk: dims c*8 .. c*8+7
    int s = rowptr[v], e = rowptr[v + 1];
    float dv = dinv[v];

    float acc[8] = {0.f, 0.f, 0.f, 0.f, 0.f, 0.f, 0.f, 0.f};

    if (g == 0) {
        uint4 u = *(const uint4*)(h + v * D + c * 8);
        float s2 = dv * dv;
        float2 f0 = bf2f(u.x), f1 = bf2f(u.y), f2 = bf2f(u.z), f3 = bf2f(u.w);
        acc[0] = s2 * f0.x; acc[1] = s2 * f0.y;
        acc[2] = s2 * f1.x; acc[3] = s2 * f1.y;
        acc[4] = s2 * f2.x; acc[5] = s2 * f2.y;
        acc[6] = s2 * f3.x; acc[7] = s2 * f3.y;
    }

    int j = s + g;
    for (; j + 4 < e; j += 8) {
        int s0 = csrc[j], s1 = csrc[j + 4];
        float w0 = dinv[s0] * dv, w1 = dinv[s1] * dv;
        uint4 ua = *(const uint4*)(h + s0 * D + c * 8);
        uint4 ub = *(const uint4*)(h + s1 * D + c * 8);
        float2 a0 = bf2f(ua.x), a1 = bf2f(ua.y), a2 = bf2f(ua.z), a3 = bf2f(ua.w);
        float2 b0 = bf2f(ub.x), b1 = bf2f(ub.y), b2 = bf2f(ub.z), b3 = bf2f(ub.w);
        acc[0] = fmaf(w0, a0.x, acc[0]); acc[1] = fmaf(w0, a0.y, acc[1]);
        acc[2] = fmaf(w0, a1.x, acc[2]); acc[3] = fmaf(w0, a1.y, acc[3]);
        acc[4] = fmaf(w0, a2.x, acc[4]); acc[5] = fmaf(w0, a2.y, acc[5]);
        acc[6] = fmaf(w0, a3.x, acc[6]); acc[7] = fmaf(w0, a3.y, acc[7]);
        acc[0] = fmaf(w1, b0.x, acc[0]); acc[1] = fmaf(w1, b0.y, acc[1]);
        acc[2] = fmaf(w1, b1.x, acc[2]); acc[3] = fmaf(w1, b1.y, acc[3]);
        acc[4] = fmaf(w1, b2.x, acc[4]); acc[5] = fmaf(w1, b2.y, acc[5]);
        acc[6] = fmaf(w1, b3.x, acc[6]); acc[7] = fmaf(w1, b3.y, acc[7]);
    }
    if (j < e) {
        int s0 = csrc[j];
        float w0 = dinv[s0] * dv;
        uint4 ua = *(const uint4*)(h + s0 * D + c * 8);
        float2 a0 = bf2f(ua.x), a1 = bf2f(ua.y), a2 = bf2f(ua.z), a3 = bf2f(ua.w);
        acc[0] = fmaf(w0, a0.x, acc[0]); acc[1] = fmaf(w0, a0.y, acc[1]);
        acc[2] = fmaf(w0, a1.x, acc[2]); acc[3] = fmaf(w0, a1.y, acc[3]);
        acc[4] = fmaf(w0, a2.x, acc[4]); acc[5] = fmaf(w0, a2.y, acc[5]);
        acc[6] = fmaf(w0, a3.x, acc[6]); acc[7] = fmaf(w0, a3.y, acc[7]);
    }

#pragma unroll
    for (int d = 0; d < 8; ++d) {
        acc[d] += __shfl_xor(acc[d], 16);
        acc[d] += __shfl_xor(acc[d], 32);
    }

    if (g == 0) {
        float4 bi0 = *(const float4*)(bias + c * 8);
        float4 bi1 = *(const float4*)(bias + c * 8 + 4);
        bf16x8 o;
        o[0] = (bf16)fmaxf(acc[0] + bi0.x, 0.f);
        o[1] = (bf16)fmaxf(acc[1] + bi0.y, 0.f);
        o[2] = (bf16)fmaxf(acc[2] + bi0.z, 0.f);
        o[3] = (bf16)fmaxf(acc[3] + bi0.w, 0.f);
        o[4] = (bf16)fmaxf(acc[4] + bi1.x, 0.f);
        o[5] = (bf16)fmaxf(acc[5] + bi1.y, 0.f);
        o[6] = (bf16)fmaxf(acc[6] + bi1.z, 0.f);
        o[7] = (bf16)fmaxf(acc[7] + bi1.w, 0.f);
        *(bf16x8*)(out + v * D + c * 8) = o;
    }
}

// fused mean-pool + 2-layer FC head: one block per graph
__global__ __launch_bounds__(256) void poolfc_kernel(const bf16* __restrict__ h,
                                                     const int* __restrict__ starts,
                                                     const float* __restrict__ Wfc,
                                                     const float* __restrict__ bfc,
                                                     const float* __restrict__ Wfc2,
                                                     const float* __restrict__ bfc2,
                                                     float* __restrict__ out) {
    __shared__ float part[3][D];
    __shared__ float pr[D];
    __shared__ float hid[D_FF];
    int g = blockIdx.x;
    int w = threadIdx.x >> 6, lane = threadIdx.x & 63;
    int s = starts[g], e = starts[g + 1];
    float ax = 0.f, ay = 0.f;
    for (int r = s + w; r < e; r += 4) {
        unsigned u = *(const unsigned*)(h + r * D + lane * 2);
        float2 f = bf2f(u);
        ax += f.x; ay += f.y;
    }
    if (w > 0) { part[w - 1][lane * 2] = ax; part[w - 1][lane * 2 + 1] = ay; }
    __syncthreads();
    if (w == 0) {
#pragma unroll
        for (int k = 0; k < 3; ++k) { ax += part[k][lane * 2]; ay += part[k][lane * 2 + 1]; }
        float c = fmaxf((float)(e - s), 1.0f);
        pr[lane * 2]     = ax / c;
        pr[lane * 2 + 1] = ay / c;
    }
    __syncthreads();
    int t = threadIdx.x;
    float acc = bfc[t];
    for (int k = 0; k < D; ++k) acc = fmaf(pr[k], Wfc[k * D_FF + t], acc);
    hid[t] = fmaxf(acc, 0.f);
    __syncthreads();
    if (t < N_CLASSES) {
        float o = bfc2[t];
        for (int k = 0; k < D_FF; ++k) o = fmaf(hid[k], Wfc2[k * N_CLASSES + t], o);
        out[g * N_CLASSES + t] = o;
    }
}

// ---------------- launch ----------------

extern "C" void kernel_launch(void* const* d_in, const int* in_sizes, int n_in,
                              void* d_out, int out_size, void* d_ws, size_t ws_size,
                              hipStream_t stream) {
    const float* x     = (const float*)d_in[0];
    const int*   eidx  = (const int*)d_in[1];
    const int*   batch = (const int*)d_in[2];
    const float* W[3]  = { (const float*)d_in[3], (const float*)d_in[5], (const float*)d_in[7] };
    const float* b[3]  = { (const float*)d_in[4], (const float*)d_in[6], (const float*)d_in[8] };
    const float* Wfc   = (const float*)d_in[9];
    const float* bfc   = (const float*)d_in[10];
    const float* Wfc2  = (const float*)d_in[11];
    const float* bfc2  = (const float*)d_in[12];
    float* out = (float*)d_out;

    const int E = in_sizes[1] / 2;           // 3,200,000
    const int N = in_sizes[0] / D;           // 100,000
    const int* esrc = eidx;
    const int* edst = eidx + E;

    uint8_t* base = (uint8_t*)d_ws;
    size_t off = 0;
    auto alloc = [&](size_t bytes) -> void* {
        void* p = base + off;
        off = (off + bytes + 255) & ~(size_t)255;
        return p;
    };
    bf16*  hA     = (bf16*) alloc((size_t)N_PAD * D * 2);
    bf16*  hB     = (bf16*) alloc((size_t)N_PAD * D * 2);
    bf16*  WT3    = (bf16*) alloc((size_t)3 * D * D * 2);
    int*   csrc   = (int*)  alloc((size_t)E * 4);
    int*   ebuf   = (int*)  alloc((size_t)E * 4);
    int*   gcount = (int*)  alloc((size_t)NBUCK * NB1 * 4);
    int*   gbase  = (int*)  alloc((size_t)(NBUCK * NB1 + 1) * 4);
    int*   rowptr = (int*)  alloc((size_t)(N + 1) * 4);
    float* dinv   = (float*)alloc((size_t)N * 4);
    int*   bsum   = (int*)  alloc(4096);
    int*   boff   = (int*)  alloc(4096);
    int*   starts = (int*)  alloc((size_t)(N_GRAPHS + 1) * 4);
    (void)ws_size; (void)n_in; (void)out_size;

    const int GB  = N_PAD / 64;                         // 1563
    const int SB  = (N + 3) / 4;                        // spmm blocks
    const int GCN = NBUCK * NB1;                        // 50176
    const int GCB = (GCN + 255) / 256;                  // 196

    // CSR build (atomic-free, LDS counting sort)
    p1_hist<<<NB1, 1024, 0, stream>>>(edst, gcount, E);
    scan1<<<GCB, 256, 0, stream>>>(gcount, gbase, bsum, GCN);
    scan2<<<1, 1024, 0, stream>>>(bsum, boff, GCB);
    scan3<<<GCB, 256, 0, stream>>>(gbase, boff, GCN);
    p3_scatter<<<NB1, 1024, 0, stream>>>(esrc, edst, gbase, ebuf, E);
    p45_fill<<<NBUCK, 1024, 0, stream>>>(ebuf, gbase, dinv, rowptr, csrc, E, N);

    // pooling segments: parallel binary search
    starts_kernel<<<1, 576, 0, stream>>>(batch, starts, N);

    // weights for all 3 layers
    castWT3_kernel<<<dim3(D, 3), D, 0, stream>>>(W[0], W[1], W[2], WT3);

    // layer 1 (f32 input, in-register cast), then layers 2-3
    gemm_f32_kernel<<<GB, 256, 0, stream>>>(x, WT3, hA, N);
    spmm_kernel<<<SB, 256, 0, stream>>>(hA, rowptr, csrc, dinv, b[0], hB, N);
    for (int l = 1; l < 3; ++l) {
        gemm_kernel<<<GB, 256, 0, stream>>>(hB, WT3 + (size_t)l * D * D, hA);
        spmm_kernel<<<SB, 256, 0, stream>>>(hA, rowptr, csrc, dinv, b[l], hB, N);
    }

    // fused mean-pool + FC head
    poolfc_kernel<<<N_GRAPHS, 256, 0, stream>>>(hB, starts, Wfc, bfc, Wfc2, bfc2, out);
}